// Round 15
// baseline (204.406 us; speedup 1.0000x reference)
//
#include <hip/hip_runtime.h>
#include <hip/hip_bf16.h>
#include <math.h>

// Sizes (fixed by the reference)
#define B_   8
#define C1_  128
#define H_   160
#define W_   160
#define HW_  25600         // 160*160
#define NSEL_ 64
#define BONUS_ 4.6875e-4f  // 0.1*0.3/64

typedef __attribute__((ext_vector_type(8))) unsigned short ushort8;
typedef __attribute__((ext_vector_type(8))) short short8;
typedef __attribute__((ext_vector_type(4))) float f32x4;

// ---------------- workspace layout (byte offsets) ----------------
#define OFF_FAC 0
#define OFF_IMP 819200
#define OFF_AW4 1638400
#define OFF_G   4915200
#define OFF_TB  5046272
#define OFF_WT  5046784
#define OFF_WPK 5636608
#define OFF_XH  5931520
#define WS_NEED_FAST 58360320ULL
// mx[b][hw][m] f32 lives in d_out[0..] as scratch; k5 overwrites it.
// xh holds bf16(x) (unscaled); k5 applies fac during staging.

__device__ __forceinline__ float sigmoidf_(float v) {
    return 1.0f / (1.0f + expf(-v));
}
__device__ __forceinline__ unsigned short f2bf(float f) {  // RNE f32->bf16
    unsigned u = __float_as_uint(f);
    return (unsigned short)((u + 0x7fffu + ((u >> 16) & 1u)) >> 16);
}
__device__ __forceinline__ float bf2f(unsigned short h) {
    return __uint_as_float(((unsigned)h) << 16);
}

// ------------------------------------------------------------------
// K0: transpose conv weights to [ic*9+tap][oc] fp32 (fallback), fold BN; tb[o]
// ------------------------------------------------------------------
__global__ void k0_wt(const float* __restrict__ wp, const float* __restrict__ gamma,
                      const float* __restrict__ beta, const float* __restrict__ mean,
                      const float* __restrict__ var, float* __restrict__ wt,
                      float* __restrict__ tb) {
    int i = blockIdx.x * 256 + threadIdx.x;
    if (i < 128) {
        float s = gamma[i] * rsqrtf(var[i] + 1e-5f);
        tb[i] = beta[i] - mean[i] * s;
    }
    if (i < 128 * 128 * 9) {
        int o  = i & 127;
        int it = i >> 7;
        float s = gamma[o] * rsqrtf(var[o] + 1e-5f);
        wt[i] = wp[o * 1152 + it] * s;
    }
}

// ------------------------------------------------------------------
// K0b: pack BN-folded weights into MFMA A-fragment order (bf16).
// flat idx = ((kstep*8+mblk)*64+l)*8+j ; kstep = tap*4+icb
// oc = mblk*16+(l&15); ic = icb*32+(l>>4)*8+j
// ------------------------------------------------------------------
__global__ void k0b_pack(const float* __restrict__ wp, const float* __restrict__ gamma,
                         const float* __restrict__ var, unsigned short* __restrict__ wpk) {
    int idx = blockIdx.x * 256 + threadIdx.x;
    if (idx >= 147456) return;
    int j = idx & 7, l = (idx >> 3) & 63, f = idx >> 9;
    int kstep = f >> 3, mblk = f & 7;
    int tap = kstep >> 2, icb = kstep & 3;
    int oc = mblk * 16 + (l & 15);
    int ic = icb * 32 + ((l >> 4) << 3) + j;
    float s = gamma[oc] * rsqrtf(var[oc] + 1e-5f);
    wpk[idx] = f2bf(wp[oc * 1152 + ic * 9 + tap] * s);
}

// ------------------------------------------------------------------
// K1a (fast, v2): NCHW fp32 -> NHWC bf16 transpose + imp (mean|x|).
// grid (100, 8) x 512.
// ------------------------------------------------------------------
__global__ __launch_bounds__(512) void k1a_convert(const float* __restrict__ x,
                                                   float* __restrict__ imp,
                                                   unsigned short* __restrict__ xh) {
    __shared__ float red[8][256];
    const int tid = threadIdx.x;
    const int l = tid & 63, g = tid >> 6;    // g: 0..7 (16 channels each)
    const int px0 = blockIdx.x * 256;
    const int b = blockIdx.y;
    const int pxl = l * 4;
    const float* xb = x + (size_t)b * C1_ * HW_ + px0 + pxl;
    unsigned short* xrb = xh + ((size_t)(b * HW_ + px0 + pxl)) * 128 + g * 16;

    float sab0 = 0.f, sab1 = 0.f, sab2 = 0.f, sab3 = 0.f;
    ushort8 v0, v1, v2, v3;
#pragma unroll
    for (int j = 0; j < 16; ++j) {
        float4 xv = *reinterpret_cast<const float4*>(xb + (size_t)(g * 16 + j) * HW_);
        sab0 += fabsf(xv.x); sab1 += fabsf(xv.y);
        sab2 += fabsf(xv.z); sab3 += fabsf(xv.w);
        const int jj = j & 7;
        v0[jj] = f2bf(xv.x); v1[jj] = f2bf(xv.y);
        v2[jj] = f2bf(xv.z); v3[jj] = f2bf(xv.w);
        if (jj == 7) {
            const int gr = j & ~7;    // 0, 8
            *reinterpret_cast<ushort8*>(xrb + 0 * 128 + gr) = v0;
            *reinterpret_cast<ushort8*>(xrb + 1 * 128 + gr) = v1;
            *reinterpret_cast<ushort8*>(xrb + 2 * 128 + gr) = v2;
            *reinterpret_cast<ushort8*>(xrb + 3 * 128 + gr) = v3;
        }
    }
    red[g][pxl + 0] = sab0; red[g][pxl + 1] = sab1;
    red[g][pxl + 2] = sab2; red[g][pxl + 3] = sab3;
    __syncthreads();
    if (tid < 256) {
        float s = 0.f;
#pragma unroll
        for (int gg = 0; gg < 8; ++gg) s += red[gg][tid];
        imp[b * HW_ + px0 + tid] = s * (1.f / 128.f);
    }
}

// ------------------------------------------------------------------
// K1 (fallback): fused MLP + imp (no xh write).
// grid (50, 8) x 256.
// ------------------------------------------------------------------
__global__ __launch_bounds__(256) void k1_mod(const float* __restrict__ x,
                                              const float* __restrict__ w_gm1,
                                              const float* __restrict__ b_gm1,
                                              const float* __restrict__ w_gm2,
                                              const float* __restrict__ b_gm2,
                                              float* __restrict__ fac,
                                              float* __restrict__ imp) {
    __shared__ float4 w1t[128 * 8];
    __shared__ float  b1s[32];
    __shared__ float  w2s[128];
    __shared__ float  b2s[4];
    const int tid = threadIdx.x;
    for (int i = tid; i < 4096; i += 256) {
        int j = i >> 7, c = i & 127;
        ((float*)w1t)[c * 32 + j] = w_gm1[i];
    }
    if (tid < 32) b1s[tid] = b_gm1[tid];
    if (tid < 128) w2s[tid] = w_gm2[tid];
    if (tid < 4) b2s[tid] = b_gm2[tid];
    __syncthreads();

    const int hw0 = blockIdx.x * 512 + tid * 2;
    const int b = blockIdx.y;
    const float* xb = x + (size_t)b * C1_ * HW_ + hw0;

    float h[2][32];
#pragma unroll
    for (int j = 0; j < 32; ++j) { h[0][j] = 0.f; h[1][j] = 0.f; }
    float sab0 = 0.f, sab1 = 0.f;
    for (int c8 = 0; c8 < 16; ++c8) {
#pragma unroll
        for (int k = 0; k < 8; ++k) {
            int c = c8 * 8 + k;
            float2 xv = *reinterpret_cast<const float2*>(xb + (size_t)c * HW_);
            sab0 += fabsf(xv.x);
            sab1 += fabsf(xv.y);
            const float4* wr = &w1t[c * 8];
#pragma unroll
            for (int j4 = 0; j4 < 8; ++j4) {
                float4 w = wr[j4];
                h[0][j4 * 4 + 0] += xv.x * w.x; h[0][j4 * 4 + 1] += xv.x * w.y;
                h[0][j4 * 4 + 2] += xv.x * w.z; h[0][j4 * 4 + 3] += xv.x * w.w;
                h[1][j4 * 4 + 0] += xv.y * w.x; h[1][j4 * 4 + 1] += xv.y * w.y;
                h[1][j4 * 4 + 2] += xv.y * w.z; h[1][j4 * 4 + 3] += xv.y * w.w;
            }
        }
    }
#pragma unroll
    for (int p = 0; p < 2; ++p) {
        float fm = 0.f;
#pragma unroll
        for (int j = 0; j < 32; ++j) h[p][j] = fmaxf(h[p][j] + b1s[j], 0.f);
#pragma unroll
        for (int m = 0; m < 4; ++m) {
            float s = b2s[m];
#pragma unroll
            for (int j = 0; j < 32; ++j) s += w2s[m * 32 + j] * h[p][j];
            fm += sigmoidf_(s);
        }
        fac[b * HW_ + hw0 + p] = 1.f + 0.07f * (fm * 0.25f);
        imp[b * HW_ + hw0 + p] = (p == 0 ? sab0 : sab1) * (1.f / 128.f);
    }
}

// ------------------------------------------------------------------
// K2: exact top-64 per batch (radix binary search on float bits).
// ------------------------------------------------------------------
__device__ __forceinline__ int blockReduceSum1024(int v, int* red, int tid) {
#pragma unroll
    for (int off = 32; off >= 1; off >>= 1) v += __shfl_down(v, off);
    if ((tid & 63) == 0) red[tid >> 6] = v;
    __syncthreads();
    if (tid < 64) {
        int s = (tid < 16) ? red[tid] : 0;
#pragma unroll
        for (int off = 8; off >= 1; off >>= 1) s += __shfl_down(s, off);
        if (tid == 0) red[16] = s;
    }
    __syncthreads();
    int r = red[16];
    __syncthreads();
    return r;
}

__global__ __launch_bounds__(1024) void k2_topk(const float* __restrict__ imp,
                                                float* __restrict__ fac) {
    __shared__ int red[17];
    __shared__ int claimed;
    const int tid = threadIdx.x;
    const int b = blockIdx.x;
    unsigned u[25];
#pragma unroll
    for (int i = 0; i < 25; ++i)
        u[i] = __float_as_uint(imp[b * HW_ + i * 1024 + tid]);

    unsigned cur = 0u;
    for (int bit = 30; bit >= 0; --bit) {
        unsigned cand = cur | (1u << bit);
        int c = 0;
#pragma unroll
        for (int i = 0; i < 25; ++i) c += (u[i] >= cand) ? 1 : 0;
        int tot = blockReduceSum1024(c, red, tid);
        if (tot >= NSEL_) cur = cand;
    }
    int cg = 0;
#pragma unroll
    for (int i = 0; i < 25; ++i) cg += (u[i] > cur) ? 1 : 0;
    int tot_gt = blockReduceSum1024(cg, red, tid);
    int need = NSEL_ - tot_gt;
    if (tid == 0) claimed = 0;
    __syncthreads();
#pragma unroll
    for (int i = 0; i < 25; ++i) {
        int idx = i * 1024 + tid;
        if (u[i] > cur) {
            fac[b * HW_ + idx] += BONUS_;
        } else if (u[i] == cur) {
            int c = atomicAdd(&claimed, 1);
            if (c < need) fac[b * HW_ + idx] += BONUS_;
        }
    }
}

// ------------------------------------------------------------------
// K3: g[b,n,ec] = guide[b,n,:] . w_gl[ec,:] + b_gl[ec]
// ------------------------------------------------------------------
__global__ __launch_bounds__(128) void k3_guide(const float* __restrict__ guide,
                                                const float* __restrict__ w_gl,
                                                const float* __restrict__ b_gl,
                                                float* __restrict__ g) {
    __shared__ float gr[512];
    const int bn = blockIdx.x;
    const int tid = threadIdx.x;
    for (int i = tid; i < 512; i += 128) gr[i] = guide[bn * 512 + i];
    __syncthreads();
    const float4* w4 = (const float4*)(w_gl + (size_t)tid * 512);
    const float4* g4 = (const float4*)gr;
    float acc = b_gl[tid];
    for (int k = 0; k < 128; ++k) {
        float4 w = w4[k]; float4 v = g4[k];
        acc += w.x * v.x + w.y * v.y + w.z * v.z + w.w * v.w;
    }
    g[bn * 128 + tid] = acc;
}

// ------------------------------------------------------------------
// K4m2 (fast, R8 version): per 128-px tile, one LDS staging of xh feeds:
//   (a) scores  mx[b][hw][m] = max_n <x, g[b,n,m,:]>
//   (b) MLP     fac = 1 + 0.0175*sum_m sigmoid(W2 relu(W1 x + b1) + b2)
// grid (200, 8) x 256.
// ------------------------------------------------------------------
__global__ __launch_bounds__(256) void k4m2_scores(const unsigned short* __restrict__ xh,
                                                   const float* __restrict__ g,
                                                   const float* __restrict__ w_gm1,
                                                   const float* __restrict__ b_gm1,
                                                   const float* __restrict__ w_gm2,
                                                   const float* __restrict__ b_gm2,
                                                   float* __restrict__ mx4,
                                                   float* __restrict__ fac) {
    __shared__ unsigned short xs[128 * 128];   // 32 KB; slot s of row holds granule s^(row&7)
    const int tid = threadIdx.x;
    const int l = tid & 63, w = tid >> 6;
    const int px0 = blockIdx.x * 128;
    const int b = blockIdx.y;

    // stage 2048 granules of 16B (LDS dest linear; source pre-swizzled)
#pragma unroll
    for (int i = 0; i < 8; ++i) {
        int idx = i * 256 + tid;
        int row = idx >> 4, gg = idx & 15;
        const char* src = (const char*)(xh + ((size_t)(b * HW_ + px0 + row)) * 128
                                        + ((gg ^ (row & 7)) * 8));
        char* dst = (char*)xs + (size_t)(i * 4096 + w * 1024);
        __builtin_amdgcn_global_load_lds((const unsigned int*)src,
                                         (unsigned int*)dst, 16, 0, 0);
    }

    const int lr = l & 15, lk = l >> 4;

    // guide A-frags (scores): A[n = nb*16+lr][k = m*32 + lk*8+j]
    short8 afr[4][2];
#pragma unroll
    for (int m = 0; m < 4; ++m)
#pragma unroll
        for (int nb = 0; nb < 2; ++nb) {
            const float* gp = g + (size_t)b * 4096 + (nb * 16 + lr) * 128
                              + m * 32 + (lk << 3);
            float4 g0 = *reinterpret_cast<const float4*>(gp);
            float4 g1 = *reinterpret_cast<const float4*>(gp + 4);
            short8 a;
            a[0] = (short)f2bf(g0.x); a[1] = (short)f2bf(g0.y);
            a[2] = (short)f2bf(g0.z); a[3] = (short)f2bf(g0.w);
            a[4] = (short)f2bf(g1.x); a[5] = (short)f2bf(g1.y);
            a[6] = (short)f2bf(g1.z); a[7] = (short)f2bf(g1.w);
            afr[m][nb] = a;
        }

    // W1 A-frags (MLP): A[oc = ob*16+lr][k = kb*32 + lk*8+j]
    short8 w1f[2][4];
#pragma unroll
    for (int ob = 0; ob < 2; ++ob)
#pragma unroll
        for (int kb = 0; kb < 4; ++kb) {
            const float* wp = w_gm1 + (size_t)(ob * 16 + lr) * 128 + kb * 32 + (lk << 3);
            float4 g0 = *reinterpret_cast<const float4*>(wp);
            float4 g1 = *reinterpret_cast<const float4*>(wp + 4);
            short8 a;
            a[0] = (short)f2bf(g0.x); a[1] = (short)f2bf(g0.y);
            a[2] = (short)f2bf(g0.z); a[3] = (short)f2bf(g0.w);
            a[4] = (short)f2bf(g1.x); a[5] = (short)f2bf(g1.y);
            a[6] = (short)f2bf(g1.z); a[7] = (short)f2bf(g1.w);
            w1f[ob][kb] = a;
        }

    // per-lane layer-2 constants
    float b1r[8], w2r[4][8];
#pragma unroll
    for (int r = 0; r < 4; ++r) {
        b1r[r] = b_gm1[lk * 4 + r];
        b1r[4 + r] = b_gm1[16 + lk * 4 + r];
    }
#pragma unroll
    for (int m = 0; m < 4; ++m)
#pragma unroll
        for (int r = 0; r < 4; ++r) {
            w2r[m][r] = w_gm2[m * 32 + lk * 4 + r];
            w2r[m][4 + r] = w_gm2[m * 32 + 16 + lk * 4 + r];
        }
    const float b20 = b_gm2[0], b21 = b_gm2[1], b22 = b_gm2[2], b23 = b_gm2[3];

    __syncthreads();   // xs ready (barrier drains vmcnt)

#pragma unroll
    for (int pxb = 0; pxb < 2; ++pxb) {
        const int px = (w * 2 + pxb) * 16 + lr;
        float mr[4];
        f32x4 h0{0.f, 0.f, 0.f, 0.f}, h1{0.f, 0.f, 0.f, 0.f};
#pragma unroll
        for (int m = 0; m < 4; ++m) {
            int gl = (m * 4 + lk) ^ (px & 7);
            short8 bf = *reinterpret_cast<const short8*>(xs + (size_t)px * 128 + gl * 8);
            f32x4 a0{0.f, 0.f, 0.f, 0.f}, a1{0.f, 0.f, 0.f, 0.f};
            a0 = __builtin_amdgcn_mfma_f32_16x16x32_bf16(afr[m][0], bf, a0, 0, 0, 0);
            a1 = __builtin_amdgcn_mfma_f32_16x16x32_bf16(afr[m][1], bf, a1, 0, 0, 0);
            h0 = __builtin_amdgcn_mfma_f32_16x16x32_bf16(w1f[0][m], bf, h0, 0, 0, 0);
            h1 = __builtin_amdgcn_mfma_f32_16x16x32_bf16(w1f[1][m], bf, h1, 0, 0, 0);
            float v = fmaxf(fmaxf(fmaxf(a0[0], a0[1]), fmaxf(a0[2], a0[3])),
                            fmaxf(fmaxf(a1[0], a1[1]), fmaxf(a1[2], a1[3])));
            v = fmaxf(v, __shfl_xor(v, 16));
            v = fmaxf(v, __shfl_xor(v, 32));
            mr[m] = v;
        }
        float s0 = b20, s1 = b21, s2 = b22, s3 = b23;
#pragma unroll
        for (int r = 0; r < 4; ++r) {
            float hv0 = fmaxf(h0[r] + b1r[r], 0.f);
            float hv1 = fmaxf(h1[r] + b1r[4 + r], 0.f);
            s0 += w2r[0][r] * hv0 + w2r[0][4 + r] * hv1;
            s1 += w2r[1][r] * hv0 + w2r[1][4 + r] * hv1;
            s2 += w2r[2][r] * hv0 + w2r[2][4 + r] * hv1;
            s3 += w2r[3][r] * hv0 + w2r[3][4 + r] * hv1;
        }
        s0 += __shfl_xor(s0, 16); s0 += __shfl_xor(s0, 32);
        s1 += __shfl_xor(s1, 16); s1 += __shfl_xor(s1, 32);
        s2 += __shfl_xor(s2, 16); s2 += __shfl_xor(s2, 32);
        s3 += __shfl_xor(s3, 16); s3 += __shfl_xor(s3, 32);
        float fm = sigmoidf_(s0) + sigmoidf_(s1) + sigmoidf_(s2) + sigmoidf_(s3);
        if (l < 16) {
            float4 o; o.x = mr[0]; o.y = mr[1]; o.z = mr[2]; o.w = mr[3];
            int hw = px0 + (w * 2 + pxb) * 16 + l;
            *reinterpret_cast<float4*>(mx4 + (size_t)(b * HW_ + hw) * 4) = o;
            fac[b * HW_ + hw] = 1.f + 0.0175f * fm;   // 0.07 * 0.25
        }
    }
}

// ------------------------------------------------------------------
// K4c: aw4[b][m][hw] = sigmoid(mx*fac/sqrt(32) + bias[m]); aw_single = mean_m
// grid (100, 8) x 256
// ------------------------------------------------------------------
__global__ __launch_bounds__(256) void k4c_aw(const float* __restrict__ mx4,
                                              const float* __restrict__ fac,
                                              const float* __restrict__ attn_bias,
                                              float* __restrict__ aw4,
                                              float* __restrict__ aw_single) {
    const int hw = blockIdx.x * 256 + threadIdx.x;
    const int b = blockIdx.y;
    float4 mv = *reinterpret_cast<const float4*>(mx4 + (size_t)(b * HW_ + hw) * 4);
    float facv = fac[b * HW_ + hw] * 0.17677669529663687f;
    float b0 = attn_bias[0], b1 = attn_bias[1], b2 = attn_bias[2], b3 = attn_bias[3];
    float a0 = sigmoidf_(mv.x * facv + b0);
    float a1 = sigmoidf_(mv.y * facv + b1);
    float a2 = sigmoidf_(mv.z * facv + b2);
    float a3 = sigmoidf_(mv.w * facv + b3);
    aw4[((size_t)(b * 4 + 0)) * HW_ + hw] = a0;
    aw4[((size_t)(b * 4 + 1)) * HW_ + hw] = a1;
    aw4[((size_t)(b * 4 + 2)) * HW_ + hw] = a2;
    aw4[((size_t)(b * 4 + 3)) * HW_ + hw] = a3;
    aw_single[b * HW_ + hw] = (a0 + a1 + a2 + a3) * 0.25f;
}

// ------------------------------------------------------------------
// K4 (fallback): aw from fp32 NCHW x.
// ------------------------------------------------------------------
__global__ __launch_bounds__(256) void k4_aw(const float* __restrict__ x,
                                             const float* __restrict__ fac,
                                             const float* __restrict__ g,
                                             const float* __restrict__ attn_bias,
                                             float* __restrict__ aw4,
                                             float* __restrict__ aw_single) {
    __shared__ float gl[4096];
    __shared__ float biass[4];
    const int tid = threadIdx.x;
    const int b = blockIdx.y;
    for (int i = tid; i < 4096; i += 256) {
        int n = i >> 7, e = i & 127;
        gl[e * 32 + n] = g[b * 4096 + i];
    }
    if (tid < 4) biass[tid] = attn_bias[tid];
    __syncthreads();
    const int hw = blockIdx.x * 256 + tid;
    const float facv = fac[b * HW_ + hw];
    const float* xb = x + (size_t)b * C1_ * HW_ + hw;
    float asum = 0.f;
#pragma unroll
    for (int m = 0; m < 4; ++m) {
        float acc[32];
#pragma unroll
        for (int n = 0; n < 32; ++n) acc[n] = 0.f;
        for (int c = 0; c < 32; ++c) {
            float xv = xb[(m * 32 + c) * HW_] * facv;
            const float4* grow = (const float4*)&gl[(m * 32 + c) * 32];
#pragma unroll
            for (int n4 = 0; n4 < 8; ++n4) {
                float4 gv = grow[n4];
                acc[n4 * 4 + 0] += xv * gv.x; acc[n4 * 4 + 1] += xv * gv.y;
                acc[n4 * 4 + 2] += xv * gv.z; acc[n4 * 4 + 3] += xv * gv.w;
            }
        }
        float mxv = acc[0];
#pragma unroll
        for (int n = 1; n < 32; ++n) mxv = fmaxf(mxv, acc[n]);
        float awv = sigmoidf_(mxv * 0.17677669529663687f + biass[m]);
        aw4[((size_t)(b * 4 + m)) * HW_ + hw] = awv;
        asum += awv;
    }
    aw_single[b * HW_ + hw] = asum * 0.25f;
}

// ------------------------------------------------------------------
// K5 (fast, v9): implicit-GEMM MFMA conv, 8 waves = (oc-split 2) x
// (px-split 2) x (K-split 2).  Halves LDS b-frag traffic vs v8 (the
// largest per-CU floor) while keeping the L2 weight stream constant.
// khalf 0 = taps 0-3, khalf 1 = taps 4-8; partial sums combined via
// LDS (xs reused, 68-float lane stride = conflict-free).
// grid (10, 20, 8), block 512.  LDS 48960 B.
// ------------------------------------------------------------------
__global__ __launch_bounds__(512, 4) void k5_mfma(const unsigned short* __restrict__ xh,
                                                  const float* __restrict__ fac,
                                                  const unsigned short* __restrict__ wpk,
                                                  const float* __restrict__ tb,
                                                  const float* __restrict__ aw4,
                                                  float* __restrict__ out) {
    __shared__ unsigned short xs[180 * 17 * 8];   // 48960 B; reused as f32 combine buf
    const int tid = threadIdx.x;
    const int l = tid & 63, w = tid >> 6;      // w: 0..7
    const int bx0 = blockIdx.x * 16;
    const int by0 = blockIdx.y * 8;
    const int b   = blockIdx.z;

    for (int i = tid; i < 2880; i += 512) {
        int gg = i & 15, pc = i >> 4;
        int hc = pc % 18, hr = pc / 18;
        int gy = by0 - 1 + hr, gx = bx0 - 1 + hc;
        ushort8 v;
#pragma unroll
        for (int k = 0; k < 8; ++k) v[k] = 0;
        if (gy >= 0 && gy < H_ && gx >= 0 && gx < W_) {
            int hw = gy * W_ + gx;
            v = *reinterpret_cast<const ushort8*>(xh + ((size_t)b * HW_ + hw) * 128 + gg * 8);
            float fv = fac[b * HW_ + hw];
#pragma unroll
            for (int k = 0; k < 8; ++k) v[k] = f2bf(bf2f(v[k]) * fv);
        }
        *reinterpret_cast<ushort8*>(xs + (size_t)(pc * 17 + gg) * 8) = v;
    }
    __syncthreads();

    const int quad = w & 3, khalf = w >> 2;
    const int qoc = quad >> 1, qpx = quad & 1;
    const int lr = l & 15, lk = l >> 4;

    f32x4 acc[4][4];
#pragma unroll
    for (int mf = 0; mf < 4; ++mf)
#pragma unroll
        for (int nf = 0; nf < 4; ++nf)
#pragma unroll
            for (int r = 0; r < 4; ++r) acc[mf][nf][r] = 0.f;

    const int tap_lo = khalf ? 4 : 0;
    const int tap_hi = khalf ? 9 : 4;
    const int kend   = tap_hi * 4;

    const unsigned short* wlane = wpk + (size_t)(qoc * 4) * 512 + (size_t)l * 8;
    const unsigned short* xbase = xs + (size_t)((qpx * 4 * 18 + lr) * 17 + lk) * 8;

    short8 A0[4];
    {
        const unsigned short* wk = wlane + (size_t)(tap_lo * 4) * 4096;
#pragma unroll
        for (int mf = 0; mf < 4; ++mf)
            A0[mf] = *reinterpret_cast<const short8*>(wk + mf * 512);
    }

#pragma unroll 1
    for (int tap = tap_lo; tap < tap_hi; ++tap) {
        const int dy = (tap >= 6) ? 2 : (tap >= 3 ? 1 : 0);
        const int dx = tap - dy * 3;
        const unsigned short* bbase = xbase + (size_t)(((dy * 18 + dx) * 17) * 8);
#pragma unroll
        for (int icb = 0; icb < 4; ++icb) {
            const int k = tap * 4 + icb;
            short8 A1[4];
            if (k + 1 < kend) {
                const unsigned short* wk = wlane + (size_t)(k + 1) * 4096;
#pragma unroll
                for (int mf = 0; mf < 4; ++mf)
                    A1[mf] = *reinterpret_cast<const short8*>(wk + mf * 512);
            }
            short8 bf[4];
#pragma unroll
            for (int nf = 0; nf < 4; ++nf)
                bf[nf] = *reinterpret_cast<const short8*>(
                    bbase + (size_t)((nf * 18 * 17 + icb * 4) * 8));
#pragma unroll
            for (int mf = 0; mf < 4; ++mf)
#pragma unroll
                for (int nf = 0; nf < 4; ++nf)
                    acc[mf][nf] = __builtin_amdgcn_mfma_f32_16x16x32_bf16(
                        A0[mf], bf[nf], acc[mf][nf], 0, 0, 0);
            if (k + 1 < kend) {
#pragma unroll
                for (int mf = 0; mf < 4; ++mf) A0[mf] = A1[mf];
            }
        }
    }

    // ---- K-combine via LDS (xs dead); 2 rounds of 2 quads (32 KB) ----
    float* cbuf = (float*)xs;
#pragma unroll 1
    for (int rnd = 0; rnd < 2; ++rnd) {
        __syncthreads();
        if (khalf == 1 && qoc == rnd) {
            float* dst = cbuf + (size_t)qpx * 4352 + (size_t)l * 68;
#pragma unroll
            for (int mf = 0; mf < 4; ++mf)
#pragma unroll
                for (int nf = 0; nf < 4; ++nf)
                    *reinterpret_cast<f32x4*>(dst + (mf * 4 + nf) * 4) = acc[mf][nf];
        }
        __syncthreads();
        if (khalf == 0 && qoc == rnd) {
            const float* src = cbuf + (size_t)qpx * 4352 + (size_t)l * 68;
#pragma unroll
            for (int mf = 0; mf < 4; ++mf)
#pragma unroll
                for (int nf = 0; nf < 4; ++nf) {
                    f32x4 v = *reinterpret_cast<const f32x4*>(src + (mf * 4 + nf) * 4);
                    acc[mf][nf][0] += v[0]; acc[mf][nf][1] += v[1];
                    acc[mf][nf][2] += v[2]; acc[mf][nf][3] += v[3];
                }
        }
    }

    // ---- epilogue: khalf==0 waves write (acc + tb) * aw ----
    if (khalf == 0) {
        const float* awb = aw4 + (size_t)b * 4 * HW_;
        float* outb = out + (size_t)b * 128 * HW_;
#pragma unroll
        for (int mf = 0; mf < 4; ++mf) {
            const int ocb = qoc * 64 + mf * 16;
            const int oc0 = ocb + lk * 4;
            const int head = ocb >> 5;
#pragma unroll
            for (int nf = 0; nf < 4; ++nf) {
                int px = qpx * 64 + nf * 16 + lr;
                int hw = (by0 + (px >> 4)) * W_ + bx0 + (px & 15);
                float aw = awb[(size_t)head * HW_ + hw];
#pragma unroll
                for (int r = 0; r < 4; ++r) {
                    int oc = oc0 + r;
                    outb[(size_t)oc * HW_ + hw] = (acc[mf][nf][r] + tb[oc]) * aw;
                }
            }
        }
    }
}

// ------------------------------------------------------------------
// K5 (fallback): fp32 direct conv
// ------------------------------------------------------------------
__global__ __launch_bounds__(256) void k5_conv(const float* __restrict__ x,
                                               const float* __restrict__ fac,
                                               const float* __restrict__ wt,
                                               const float* __restrict__ tb,
                                               const float* __restrict__ aw4,
                                               float* __restrict__ out) {
    __shared__ float ft[18][36];
    __shared__ float xs[16][18][36];
    __shared__ float wl[16][9][32];
    const int tx = threadIdx.x;
    const int ty = threadIdx.y;
    const int tid = ty * 32 + tx;
    const int bx0 = blockIdx.x * 32;
    const int by0 = blockIdx.y * 16;
    const int m = blockIdx.z & 3;
    const int b = blockIdx.z >> 2;

    for (int i = tid; i < 18 * 34; i += 256) {
        int r = i / 34, c = i - r * 34;
        int gy = by0 - 1 + r, gx = bx0 - 1 + c;
        bool in = (gy >= 0) && (gy < H_) && (gx < W_) && (gx >= 0);
        ft[r][c] = in ? fac[b * HW_ + gy * W_ + gx] : 0.f;
    }
    float acc0[32], acc1[32];
#pragma unroll
    for (int i = 0; i < 32; ++i) { acc0[i] = 0.f; acc1[i] = 0.f; }
    __syncthreads();

    for (int icc = 0; icc < 8; ++icc) {
        const int ic0 = icc * 16;
        for (int i = tid; i < 4608; i += 256) {
            int ic = i / 288; int rem = i - ic * 288;
            int tap = rem >> 5; int oc = rem & 31;
            wl[ic][tap][oc] = wt[((ic0 + ic) * 9 + tap) * 128 + m * 32 + oc];
        }
        for (int i = tid; i < 16 * 612; i += 256) {
            int ic = i / 612; int j = i - ic * 612;
            int r = j / 34; int c = j - r * 34;
            int gy = by0 - 1 + r, gx = bx0 - 1 + c;
            int gyc = min(max(gy, 0), H_ - 1), gxc = min(max(gx, 0), W_ - 1);
            xs[ic][r][c] = x[((size_t)(b * C1_ + ic0 + ic)) * HW_ + gyc * W_ + gxc] * ft[r][c];
        }
        __syncthreads();
        for (int ic = 0; ic < 16; ++ic) {
#pragma unroll
            for (int ky = 0; ky < 3; ++ky) {
#pragma unroll
                for (int kx = 0; kx < 3; ++kx) {
                    float xv0 = xs[ic][ty + ky][tx + kx];
                    float xv1 = xs[ic][ty + 8 + ky][tx + kx];
                    const float4* wp = (const float4*)&wl[ic][ky * 3 + kx][0];
#pragma unroll
                    for (int o4 = 0; o4 < 8; ++o4) {
                        float4 wv = wp[o4];
                        acc0[o4 * 4 + 0] += xv0 * wv.x; acc0[o4 * 4 + 1] += xv0 * wv.y;
                        acc0[o4 * 4 + 2] += xv0 * wv.z; acc0[o4 * 4 + 3] += xv0 * wv.w;
                        acc1[o4 * 4 + 0] += xv1 * wv.x; acc1[o4 * 4 + 1] += xv1 * wv.y;
                        acc1[o4 * 4 + 2] += xv1 * wv.z; acc1[o4 * 4 + 3] += xv1 * wv.w;
                    }
                }
            }
        }
        __syncthreads();
    }

    const int hw0 = (by0 + ty) * W_ + bx0 + tx;
    const int hw1 = (by0 + ty + 8) * W_ + bx0 + tx;
    const float aw0 = aw4[((size_t)(b * 4 + m)) * HW_ + hw0];
    const float aw1 = aw4[((size_t)(b * 4 + m)) * HW_ + hw1];
    float* ob = out + ((size_t)(b * C1_ + m * 32)) * HW_;
#pragma unroll
    for (int oc = 0; oc < 32; ++oc) {
        float t = tb[m * 32 + oc];
        ob[oc * HW_ + hw0] = (acc0[oc] + t) * aw0;
        ob[oc * HW_ + hw1] = (acc1[oc] + t) * aw1;
    }
}

// ------------------------------------------------------------------
extern "C" void kernel_launch(void* const* d_in, const int* in_sizes, int n_in,
                              void* d_out, int out_size, void* d_ws, size_t ws_size,
                              hipStream_t stream) {
    const float* x        = (const float*)d_in[0];
    const float* guide    = (const float*)d_in[1];
    const float* w_gm1    = (const float*)d_in[2];
    const float* b_gm1    = (const float*)d_in[3];
    const float* w_gm2    = (const float*)d_in[4];
    const float* b_gm2    = (const float*)d_in[5];
    // d_in[6..10]: w_qkv, w_ge1, b_ge1, w_ge2, b_ge2 -- mathematically unused
    const float* w_gl     = (const float*)d_in[11];
    const float* b_gl     = (const float*)d_in[12];
    const float* attn_bias= (const float*)d_in[13];
    const float* w_proj   = (const float*)d_in[14];
    const float* bn_gamma = (const float*)d_in[15];
    const float* bn_beta  = (const float*)d_in[16];
    const float* bn_mean  = (const float*)d_in[17];
    const float* bn_var   = (const float*)d_in[18];

    char* wsb = (char*)d_ws;
    float* fac = (float*)(wsb + OFF_FAC);
    float* imp = (float*)(wsb + OFF_IMP);
    float* aw4 = (float*)(wsb + OFF_AW4);
    float* g   = (float*)(wsb + OFF_G);
    float* tb  = (float*)(wsb + OFF_TB);
    float* wt  = (float*)(wsb + OFF_WT);
    unsigned short* wpk = (unsigned short*)(wsb + OFF_WPK);
    unsigned short* xh  = (unsigned short*)(wsb + OFF_XH);

    float* out0 = (float*)d_out;
    float* out1 = (float*)d_out + (size_t)B_ * C1_ * HW_;
    float* mx4  = (float*)d_out;   // scratch in d_out; k4c consumes it, k5 overwrites

    const bool fast = (ws_size >= WS_NEED_FAST);

    k0_wt<<<dim3(576), dim3(256), 0, stream>>>(w_proj, bn_gamma, bn_beta, bn_mean, bn_var, wt, tb);
    if (fast) {
        k0b_pack<<<dim3(576), dim3(256), 0, stream>>>(w_proj, bn_gamma, bn_var, wpk);
        k1a_convert<<<dim3(100, 8), dim3(512), 0, stream>>>(x, imp, xh);
        k3_guide<<<dim3(256), dim3(128), 0, stream>>>(guide, w_gl, b_gl, g);
        k4m2_scores<<<dim3(200, 8), dim3(256), 0, stream>>>(xh, g, w_gm1, b_gm1,
                                                            w_gm2, b_gm2, mx4, fac);
        k2_topk<<<dim3(8), dim3(1024), 0, stream>>>(imp, fac);
        k4c_aw<<<dim3(100, 8), dim3(256), 0, stream>>>(mx4, fac, attn_bias, aw4, out1);
        k5_mfma<<<dim3(10, 20, 8), dim3(512), 0, stream>>>(xh, fac, wpk, tb, aw4, out0);
    } else {
        k1_mod<<<dim3(50, 8), dim3(256), 0, stream>>>(x, w_gm1, b_gm1, w_gm2, b_gm2,
                                                      fac, imp);
        k3_guide<<<dim3(256), dim3(128), 0, stream>>>(guide, w_gl, b_gl, g);
        k2_topk<<<dim3(8), dim3(1024), 0, stream>>>(imp, fac);
        k4_aw<<<dim3(100, 8), dim3(256), 0, stream>>>(x, fac, g, attn_bias, aw4, out1);
        k5_conv<<<dim3(5, 10, B_ * 4), dim3(32, 8), 0, stream>>>(x, fac, wt, tb, aw4, out0);
    }
}

// Round 16
// 196.613 us; speedup vs baseline: 1.0396x; 1.0396x over previous
//
#include <hip/hip_runtime.h>
#include <hip/hip_bf16.h>
#include <math.h>

// Sizes (fixed by the reference)
#define B_   8
#define C1_  128
#define H_   160
#define W_   160
#define HW_  25600         // 160*160
#define NSEL_ 64
#define BONUS_ 4.6875e-4f  // 0.1*0.3/64

typedef __attribute__((ext_vector_type(8))) unsigned short ushort8;
typedef __attribute__((ext_vector_type(8))) short short8;
typedef __attribute__((ext_vector_type(4))) float f32x4;

// ---------------- workspace layout (byte offsets) ----------------
#define OFF_FAC 0
#define OFF_IMP 819200
#define OFF_AW4 1638400
#define OFF_G   4915200
#define OFF_TB  5046272
#define OFF_WT  5046784
#define OFF_WPK 5636608
#define OFF_XH  5931520
#define WS_NEED_FAST 58360320ULL
// xh holds bf16(x) (unscaled); k5 applies fac during staging.
// fac pipeline (fast): k2 writes bonus|0 -> k4m2 adds 1+0.0175*fm (final).

__device__ __forceinline__ float sigmoidf_(float v) {
    return 1.0f / (1.0f + expf(-v));
}
__device__ __forceinline__ unsigned short f2bf(float f) {  // RNE f32->bf16
    unsigned u = __float_as_uint(f);
    return (unsigned short)((u + 0x7fffu + ((u >> 16) & 1u)) >> 16);
}
__device__ __forceinline__ float bf2f(unsigned short h) {
    return __uint_as_float(((unsigned)h) << 16);
}

// ------------------------------------------------------------------
// K_PREP: fused k0_wt + k0b_pack + k3_guide (independent prep work).
// blocks [0,576): BN-folded fp32 wt + tb;  [576,1152): MFMA-packed wpk;
// [1152,1280): guide GEMM g (2 rows per block).  grid 1280 x 256.
// ------------------------------------------------------------------
__global__ __launch_bounds__(256) void k_prep(const float* __restrict__ wp,
                                              const float* __restrict__ gamma,
                                              const float* __restrict__ beta,
                                              const float* __restrict__ mean,
                                              const float* __restrict__ var,
                                              const float* __restrict__ guide,
                                              const float* __restrict__ w_gl,
                                              const float* __restrict__ b_gl,
                                              float* __restrict__ wt,
                                              float* __restrict__ tb,
                                              unsigned short* __restrict__ wpk,
                                              float* __restrict__ g) {
    const int blk = blockIdx.x;
    const int tid = threadIdx.x;
    if (blk < 576) {
        int i = blk * 256 + tid;
        if (i < 128) {
            float s = gamma[i] * rsqrtf(var[i] + 1e-5f);
            tb[i] = beta[i] - mean[i] * s;
        }
        if (i < 147456) {
            int o = i & 127, it = i >> 7;
            float s = gamma[o] * rsqrtf(var[o] + 1e-5f);
            wt[i] = wp[o * 1152 + it] * s;
        }
    } else if (blk < 1152) {
        int idx = (blk - 576) * 256 + tid;
        if (idx < 147456) {
            int j = idx & 7, l = (idx >> 3) & 63, f = idx >> 9;
            int kstep = f >> 3, mblk = f & 7;
            int tap = kstep >> 2, icb = kstep & 3;
            int oc = mblk * 16 + (l & 15);
            int ic = icb * 32 + ((l >> 4) << 3) + j;
            float s = gamma[oc] * rsqrtf(var[oc] + 1e-5f);
            wpk[idx] = f2bf(wp[oc * 1152 + ic * 9 + tap] * s);
        }
    } else {
        __shared__ float gr[2][512];
        const int half = tid >> 7, t = tid & 127;
        const int bn = (blk - 1152) * 2 + half;
        for (int i = t; i < 512; i += 128) gr[half][i] = guide[bn * 512 + i];
        __syncthreads();
        const float4* w4 = (const float4*)(w_gl + (size_t)t * 512);
        const float4* g4 = (const float4*)gr[half];
        float acc = b_gl[t];
        for (int k = 0; k < 128; ++k) {
            float4 w = w4[k]; float4 v = g4[k];
            acc += w.x * v.x + w.y * v.y + w.z * v.z + w.w * v.w;
        }
        g[bn * 128 + t] = acc;
    }
}

// ------------------------------------------------------------------
// K1a (fast, v2): NCHW fp32 -> NHWC bf16 transpose + imp (mean|x|).
// grid (100, 8) x 512.
// ------------------------------------------------------------------
__global__ __launch_bounds__(512) void k1a_convert(const float* __restrict__ x,
                                                   float* __restrict__ imp,
                                                   unsigned short* __restrict__ xh) {
    __shared__ float red[8][256];
    const int tid = threadIdx.x;
    const int l = tid & 63, g = tid >> 6;    // g: 0..7 (16 channels each)
    const int px0 = blockIdx.x * 256;
    const int b = blockIdx.y;
    const int pxl = l * 4;
    const float* xb = x + (size_t)b * C1_ * HW_ + px0 + pxl;
    unsigned short* xrb = xh + ((size_t)(b * HW_ + px0 + pxl)) * 128 + g * 16;

    float sab0 = 0.f, sab1 = 0.f, sab2 = 0.f, sab3 = 0.f;
    ushort8 v0, v1, v2, v3;
#pragma unroll
    for (int j = 0; j < 16; ++j) {
        float4 xv = *reinterpret_cast<const float4*>(xb + (size_t)(g * 16 + j) * HW_);
        sab0 += fabsf(xv.x); sab1 += fabsf(xv.y);
        sab2 += fabsf(xv.z); sab3 += fabsf(xv.w);
        const int jj = j & 7;
        v0[jj] = f2bf(xv.x); v1[jj] = f2bf(xv.y);
        v2[jj] = f2bf(xv.z); v3[jj] = f2bf(xv.w);
        if (jj == 7) {
            const int gr = j & ~7;    // 0, 8
            *reinterpret_cast<ushort8*>(xrb + 0 * 128 + gr) = v0;
            *reinterpret_cast<ushort8*>(xrb + 1 * 128 + gr) = v1;
            *reinterpret_cast<ushort8*>(xrb + 2 * 128 + gr) = v2;
            *reinterpret_cast<ushort8*>(xrb + 3 * 128 + gr) = v3;
        }
    }
    red[g][pxl + 0] = sab0; red[g][pxl + 1] = sab1;
    red[g][pxl + 2] = sab2; red[g][pxl + 3] = sab3;
    __syncthreads();
    if (tid < 256) {
        float s = 0.f;
#pragma unroll
        for (int gg = 0; gg < 8; ++gg) s += red[gg][tid];
        imp[b * HW_ + px0 + tid] = s * (1.f / 128.f);
    }
}

// ------------------------------------------------------------------
// K1 (fallback): fused MLP + imp (no xh write).
// grid (50, 8) x 256.
// ------------------------------------------------------------------
__global__ __launch_bounds__(256) void k1_mod(const float* __restrict__ x,
                                              const float* __restrict__ w_gm1,
                                              const float* __restrict__ b_gm1,
                                              const float* __restrict__ w_gm2,
                                              const float* __restrict__ b_gm2,
                                              float* __restrict__ fac,
                                              float* __restrict__ imp) {
    __shared__ float4 w1t[128 * 8];
    __shared__ float  b1s[32];
    __shared__ float  w2s[128];
    __shared__ float  b2s[4];
    const int tid = threadIdx.x;
    for (int i = tid; i < 4096; i += 256) {
        int j = i >> 7, c = i & 127;
        ((float*)w1t)[c * 32 + j] = w_gm1[i];
    }
    if (tid < 32) b1s[tid] = b_gm1[tid];
    if (tid < 128) w2s[tid] = w_gm2[tid];
    if (tid < 4) b2s[tid] = b_gm2[tid];
    __syncthreads();

    const int hw0 = blockIdx.x * 512 + tid * 2;
    const int b = blockIdx.y;
    const float* xb = x + (size_t)b * C1_ * HW_ + hw0;

    float h[2][32];
#pragma unroll
    for (int j = 0; j < 32; ++j) { h[0][j] = 0.f; h[1][j] = 0.f; }
    float sab0 = 0.f, sab1 = 0.f;
    for (int c8 = 0; c8 < 16; ++c8) {
#pragma unroll
        for (int k = 0; k < 8; ++k) {
            int c = c8 * 8 + k;
            float2 xv = *reinterpret_cast<const float2*>(xb + (size_t)c * HW_);
            sab0 += fabsf(xv.x);
            sab1 += fabsf(xv.y);
            const float4* wr = &w1t[c * 8];
#pragma unroll
            for (int j4 = 0; j4 < 8; ++j4) {
                float4 w = wr[j4];
                h[0][j4 * 4 + 0] += xv.x * w.x; h[0][j4 * 4 + 1] += xv.x * w.y;
                h[0][j4 * 4 + 2] += xv.x * w.z; h[0][j4 * 4 + 3] += xv.x * w.w;
                h[1][j4 * 4 + 0] += xv.y * w.x; h[1][j4 * 4 + 1] += xv.y * w.y;
                h[1][j4 * 4 + 2] += xv.y * w.z; h[1][j4 * 4 + 3] += xv.y * w.w;
            }
        }
    }
#pragma unroll
    for (int p = 0; p < 2; ++p) {
        float fm = 0.f;
#pragma unroll
        for (int j = 0; j < 32; ++j) h[p][j] = fmaxf(h[p][j] + b1s[j], 0.f);
#pragma unroll
        for (int m = 0; m < 4; ++m) {
            float s = b2s[m];
#pragma unroll
            for (int j = 0; j < 32; ++j) s += w2s[m * 32 + j] * h[p][j];
            fm += sigmoidf_(s);
        }
        fac[b * HW_ + hw0 + p] = 1.f + 0.07f * (fm * 0.25f);
        imp[b * HW_ + hw0 + p] = (p == 0 ? sab0 : sab1) * (1.f / 128.f);
    }
}

// ------------------------------------------------------------------
// K2: exact top-64 per batch (radix binary search on float bits).
// mode 1 (fast): fac[idx] = selected ? BONUS : 0   (init for k4m2)
// mode 0 (fallback): fac[idx] += BONUS for selected only.
// ------------------------------------------------------------------
__device__ __forceinline__ int blockReduceSum1024(int v, int* red, int tid) {
#pragma unroll
    for (int off = 32; off >= 1; off >>= 1) v += __shfl_down(v, off);
    if ((tid & 63) == 0) red[tid >> 6] = v;
    __syncthreads();
    if (tid < 64) {
        int s = (tid < 16) ? red[tid] : 0;
#pragma unroll
        for (int off = 8; off >= 1; off >>= 1) s += __shfl_down(s, off);
        if (tid == 0) red[16] = s;
    }
    __syncthreads();
    int r = red[16];
    __syncthreads();
    return r;
}

__global__ __launch_bounds__(1024) void k2_topk(const float* __restrict__ imp,
                                                float* __restrict__ fac,
                                                int mode) {
    __shared__ int red[17];
    __shared__ int claimed;
    const int tid = threadIdx.x;
    const int b = blockIdx.x;
    unsigned u[25];
#pragma unroll
    for (int i = 0; i < 25; ++i)
        u[i] = __float_as_uint(imp[b * HW_ + i * 1024 + tid]);

    unsigned cur = 0u;
    for (int bit = 30; bit >= 0; --bit) {
        unsigned cand = cur | (1u << bit);
        int c = 0;
#pragma unroll
        for (int i = 0; i < 25; ++i) c += (u[i] >= cand) ? 1 : 0;
        int tot = blockReduceSum1024(c, red, tid);
        if (tot >= NSEL_) cur = cand;
    }
    int cg = 0;
#pragma unroll
    for (int i = 0; i < 25; ++i) cg += (u[i] > cur) ? 1 : 0;
    int tot_gt = blockReduceSum1024(cg, red, tid);
    int need = NSEL_ - tot_gt;
    if (tid == 0) claimed = 0;
    __syncthreads();
#pragma unroll
    for (int i = 0; i < 25; ++i) {
        int idx = i * 1024 + tid;
        float v = 0.f;
        if (u[i] > cur) {
            v = BONUS_;
        } else if (u[i] == cur) {
            int c = atomicAdd(&claimed, 1);
            if (c < need) v = BONUS_;
        }
        if (mode) fac[b * HW_ + idx] = v;
        else if (v != 0.f) fac[b * HW_ + idx] += v;
    }
}

// ------------------------------------------------------------------
// K4m2 (fast, v4): per 128-px tile, one LDS staging of xh feeds:
//   (a) scores  mx[m] = max_n <x, g[b,n,m,:]>   (kept in registers)
//   (b) MLP     fm -> fac = 1 + 0.0175*fm + bonus  (bonus pre-written by k2)
//   (c) fused aw: aw4[b][m][hw] = sigmoid(mx*fac/sqrt(32)+bias[m]),
//       aw_single = mean_m  (k4c eliminated; mx4 buffer eliminated)
// grid (200, 8) x 256.
// ------------------------------------------------------------------
__global__ __launch_bounds__(256) void k4m2_scores(const unsigned short* __restrict__ xh,
                                                   const float* __restrict__ g,
                                                   const float* __restrict__ w_gm1,
                                                   const float* __restrict__ b_gm1,
                                                   const float* __restrict__ w_gm2,
                                                   const float* __restrict__ b_gm2,
                                                   const float* __restrict__ attn_bias,
                                                   float* __restrict__ fac,
                                                   float* __restrict__ aw4,
                                                   float* __restrict__ aw_single) {
    __shared__ unsigned short xs[128 * 128];   // 32 KB; slot s of row holds granule s^(row&7)
    const int tid = threadIdx.x;
    const int l = tid & 63, w = tid >> 6;
    const int px0 = blockIdx.x * 128;
    const int b = blockIdx.y;

    // stage 2048 granules of 16B (LDS dest linear; source pre-swizzled)
#pragma unroll
    for (int i = 0; i < 8; ++i) {
        int idx = i * 256 + tid;
        int row = idx >> 4, gg = idx & 15;
        const char* src = (const char*)(xh + ((size_t)(b * HW_ + px0 + row)) * 128
                                        + ((gg ^ (row & 7)) * 8));
        char* dst = (char*)xs + (size_t)(i * 4096 + w * 1024);
        __builtin_amdgcn_global_load_lds((const unsigned int*)src,
                                         (unsigned int*)dst, 16, 0, 0);
    }

    const int lr = l & 15, lk = l >> 4;

    // guide A-frags (scores): A[n = nb*16+lr][k = m*32 + lk*8+j]
    short8 afr[4][2];
#pragma unroll
    for (int m = 0; m < 4; ++m)
#pragma unroll
        for (int nb = 0; nb < 2; ++nb) {
            const float* gp = g + (size_t)b * 4096 + (nb * 16 + lr) * 128
                              + m * 32 + (lk << 3);
            float4 g0 = *reinterpret_cast<const float4*>(gp);
            float4 g1 = *reinterpret_cast<const float4*>(gp + 4);
            short8 a;
            a[0] = (short)f2bf(g0.x); a[1] = (short)f2bf(g0.y);
            a[2] = (short)f2bf(g0.z); a[3] = (short)f2bf(g0.w);
            a[4] = (short)f2bf(g1.x); a[5] = (short)f2bf(g1.y);
            a[6] = (short)f2bf(g1.z); a[7] = (short)f2bf(g1.w);
            afr[m][nb] = a;
        }

    // W1 A-frags (MLP): A[oc = ob*16+lr][k = kb*32 + lk*8+j]
    short8 w1f[2][4];
#pragma unroll
    for (int ob = 0; ob < 2; ++ob)
#pragma unroll
        for (int kb = 0; kb < 4; ++kb) {
            const float* wp = w_gm1 + (size_t)(ob * 16 + lr) * 128 + kb * 32 + (lk << 3);
            float4 g0 = *reinterpret_cast<const float4*>(wp);
            float4 g1 = *reinterpret_cast<const float4*>(wp + 4);
            short8 a;
            a[0] = (short)f2bf(g0.x); a[1] = (short)f2bf(g0.y);
            a[2] = (short)f2bf(g0.z); a[3] = (short)f2bf(g0.w);
            a[4] = (short)f2bf(g1.x); a[5] = (short)f2bf(g1.y);
            a[6] = (short)f2bf(g1.z); a[7] = (short)f2bf(g1.w);
            w1f[ob][kb] = a;
        }

    // per-lane layer-2 constants
    float b1r[8], w2r[4][8];
#pragma unroll
    for (int r = 0; r < 4; ++r) {
        b1r[r] = b_gm1[lk * 4 + r];
        b1r[4 + r] = b_gm1[16 + lk * 4 + r];
    }
#pragma unroll
    for (int m = 0; m < 4; ++m)
#pragma unroll
        for (int r = 0; r < 4; ++r) {
            w2r[m][r] = w_gm2[m * 32 + lk * 4 + r];
            w2r[m][4 + r] = w_gm2[m * 32 + 16 + lk * 4 + r];
        }
    const float b20 = b_gm2[0], b21 = b_gm2[1], b22 = b_gm2[2], b23 = b_gm2[3];
    const float ab0 = attn_bias[0], ab1 = attn_bias[1];
    const float ab2 = attn_bias[2], ab3 = attn_bias[3];

    __syncthreads();   // xs ready (barrier drains vmcnt)

#pragma unroll
    for (int pxb = 0; pxb < 2; ++pxb) {
        const int px = (w * 2 + pxb) * 16 + lr;
        float mr[4];
        f32x4 h0{0.f, 0.f, 0.f, 0.f}, h1{0.f, 0.f, 0.f, 0.f};
#pragma unroll
        for (int m = 0; m < 4; ++m) {
            int gl = (m * 4 + lk) ^ (px & 7);
            short8 bf = *reinterpret_cast<const short8*>(xs + (size_t)px * 128 + gl * 8);
            f32x4 a0{0.f, 0.f, 0.f, 0.f}, a1{0.f, 0.f, 0.f, 0.f};
            a0 = __builtin_amdgcn_mfma_f32_16x16x32_bf16(afr[m][0], bf, a0, 0, 0, 0);
            a1 = __builtin_amdgcn_mfma_f32_16x16x32_bf16(afr[m][1], bf, a1, 0, 0, 0);
            h0 = __builtin_amdgcn_mfma_f32_16x16x32_bf16(w1f[0][m], bf, h0, 0, 0, 0);
            h1 = __builtin_amdgcn_mfma_f32_16x16x32_bf16(w1f[1][m], bf, h1, 0, 0, 0);
            float v = fmaxf(fmaxf(fmaxf(a0[0], a0[1]), fmaxf(a0[2], a0[3])),
                            fmaxf(fmaxf(a1[0], a1[1]), fmaxf(a1[2], a1[3])));
            v = fmaxf(v, __shfl_xor(v, 16));
            v = fmaxf(v, __shfl_xor(v, 32));
            mr[m] = v;
        }
        float s0 = b20, s1 = b21, s2 = b22, s3 = b23;
#pragma unroll
        for (int r = 0; r < 4; ++r) {
            float hv0 = fmaxf(h0[r] + b1r[r], 0.f);
            float hv1 = fmaxf(h1[r] + b1r[4 + r], 0.f);
            s0 += w2r[0][r] * hv0 + w2r[0][4 + r] * hv1;
            s1 += w2r[1][r] * hv0 + w2r[1][4 + r] * hv1;
            s2 += w2r[2][r] * hv0 + w2r[2][4 + r] * hv1;
            s3 += w2r[3][r] * hv0 + w2r[3][4 + r] * hv1;
        }
        s0 += __shfl_xor(s0, 16); s0 += __shfl_xor(s0, 32);
        s1 += __shfl_xor(s1, 16); s1 += __shfl_xor(s1, 32);
        s2 += __shfl_xor(s2, 16); s2 += __shfl_xor(s2, 32);
        s3 += __shfl_xor(s3, 16); s3 += __shfl_xor(s3, 32);
        float fm = sigmoidf_(s0) + sigmoidf_(s1) + sigmoidf_(s2) + sigmoidf_(s3);
        if (l < 16) {
            int hw = px0 + (w * 2 + pxb) * 16 + l;
            float bonus = fac[b * HW_ + hw];             // from k2 (BONUS or 0)
            float fv = 1.f + 0.0175f * fm + bonus;       // 0.07 * 0.25
            fac[b * HW_ + hw] = fv;
            float sc = fv * 0.17677669529663687f;
            float a0 = sigmoidf_(mr[0] * sc + ab0);
            float a1 = sigmoidf_(mr[1] * sc + ab1);
            float a2 = sigmoidf_(mr[2] * sc + ab2);
            float a3 = sigmoidf_(mr[3] * sc + ab3);
            aw4[((size_t)(b * 4 + 0)) * HW_ + hw] = a0;
            aw4[((size_t)(b * 4 + 1)) * HW_ + hw] = a1;
            aw4[((size_t)(b * 4 + 2)) * HW_ + hw] = a2;
            aw4[((size_t)(b * 4 + 3)) * HW_ + hw] = a3;
            aw_single[b * HW_ + hw] = (a0 + a1 + a2 + a3) * 0.25f;
        }
    }
}

// ------------------------------------------------------------------
// K4 (fallback): aw from fp32 NCHW x.
// ------------------------------------------------------------------
__global__ __launch_bounds__(256) void k4_aw(const float* __restrict__ x,
                                             const float* __restrict__ fac,
                                             const float* __restrict__ g,
                                             const float* __restrict__ attn_bias,
                                             float* __restrict__ aw4,
                                             float* __restrict__ aw_single) {
    __shared__ float gl[4096];
    __shared__ float biass[4];
    const int tid = threadIdx.x;
    const int b = blockIdx.y;
    for (int i = tid; i < 4096; i += 256) {
        int n = i >> 7, e = i & 127;
        gl[e * 32 + n] = g[b * 4096 + i];
    }
    if (tid < 4) biass[tid] = attn_bias[tid];
    __syncthreads();
    const int hw = blockIdx.x * 256 + tid;
    const float facv = fac[b * HW_ + hw];
    const float* xb = x + (size_t)b * C1_ * HW_ + hw;
    float asum = 0.f;
#pragma unroll
    for (int m = 0; m < 4; ++m) {
        float acc[32];
#pragma unroll
        for (int n = 0; n < 32; ++n) acc[n] = 0.f;
        for (int c = 0; c < 32; ++c) {
            float xv = xb[(m * 32 + c) * HW_] * facv;
            const float4* grow = (const float4*)&gl[(m * 32 + c) * 32];
#pragma unroll
            for (int n4 = 0; n4 < 8; ++n4) {
                float4 gv = grow[n4];
                acc[n4 * 4 + 0] += xv * gv.x; acc[n4 * 4 + 1] += xv * gv.y;
                acc[n4 * 4 + 2] += xv * gv.z; acc[n4 * 4 + 3] += xv * gv.w;
            }
        }
        float mxv = acc[0];
#pragma unroll
        for (int n = 1; n < 32; ++n) mxv = fmaxf(mxv, acc[n]);
        float awv = sigmoidf_(mxv * 0.17677669529663687f + biass[m]);
        aw4[((size_t)(b * 4 + m)) * HW_ + hw] = awv;
        asum += awv;
    }
    aw_single[b * HW_ + hw] = asum * 0.25f;
}

// ------------------------------------------------------------------
// K5 (fast, v8): implicit-GEMM MFMA conv, 512 threads / 8 waves per
// block (128px x 128oc tile; each wave = 32oc x 64px).  R13/R14-verified
// best variant (74 us): K-split (v9) and other variants were neutral.
// grid (10, 20, 8), block 512.  LDS 48960 B.
// ------------------------------------------------------------------
__global__ __launch_bounds__(512, 4) void k5_mfma(const unsigned short* __restrict__ xh,
                                                  const float* __restrict__ fac,
                                                  const unsigned short* __restrict__ wpk,
                                                  const float* __restrict__ tb,
                                                  const float* __restrict__ aw4,
                                                  float* __restrict__ out) {
    __shared__ unsigned short xs[180 * 17 * 8];
    const int tid = threadIdx.x;
    const int l = tid & 63, w = tid >> 6;      // w: 0..7
    const int bx0 = blockIdx.x * 16;
    const int by0 = blockIdx.y * 8;
    const int b   = blockIdx.z;

    for (int i = tid; i < 2880; i += 512) {
        int gg = i & 15, pc = i >> 4;
        int hc = pc % 18, hr = pc / 18;
        int gy = by0 - 1 + hr, gx = bx0 - 1 + hc;
        ushort8 v;
#pragma unroll
        for (int k = 0; k < 8; ++k) v[k] = 0;
        if (gy >= 0 && gy < H_ && gx >= 0 && gx < W_) {
            int hw = gy * W_ + gx;
            v = *reinterpret_cast<const ushort8*>(xh + ((size_t)b * HW_ + hw) * 128 + gg * 8);
            float fv = fac[b * HW_ + hw];
#pragma unroll
            for (int k = 0; k < 8; ++k) v[k] = f2bf(bf2f(v[k]) * fv);
        }
        *reinterpret_cast<ushort8*>(xs + (size_t)(pc * 17 + gg) * 8) = v;
    }
    __syncthreads();

    const int qo = w >> 1;        // oc quarter: 32 oc (= mblks qo*2, qo*2+1)
    const int phalf = w & 1;      // px half: 64 px
    const int lr = l & 15, lk = l >> 4;

    f32x4 acc[2][4];
#pragma unroll
    for (int mf = 0; mf < 2; ++mf)
#pragma unroll
        for (int nf = 0; nf < 4; ++nf)
#pragma unroll
            for (int r = 0; r < 4; ++r) acc[mf][nf][r] = 0.f;

    const unsigned short* wlane = wpk + (size_t)(qo * 2) * 512 + (size_t)l * 8;
    const unsigned short* xbase = xs + (size_t)((phalf * 4 * 18 + lr) * 17 + lk) * 8;

    short8 A0[2], A1[2];
#pragma unroll
    for (int mf = 0; mf < 2; ++mf) {
        A0[mf] = *reinterpret_cast<const short8*>(wlane + mf * 512);
        A1[mf] = *reinterpret_cast<const short8*>(wlane + 4096 + mf * 512);
    }

#pragma unroll 1
    for (int tap = 0; tap < 9; ++tap) {
        const int dy = (tap >= 6) ? 2 : (tap >= 3 ? 1 : 0);
        const int dx = tap - dy * 3;
        const unsigned short* bbase = xbase + (size_t)(((dy * 18 + dx) * 17) * 8);
        const unsigned short* wpre = wlane + (size_t)(tap * 4 + 2) * 4096;
#pragma unroll
        for (int icb = 0; icb < 4; ++icb) {
            const int k = tap * 4 + icb;
            short8 A2[2];
            if (k + 2 < 36) {
#pragma unroll
                for (int mf = 0; mf < 2; ++mf)
                    A2[mf] = *reinterpret_cast<const short8*>(wpre + (size_t)icb * 4096 + mf * 512);
            }
            short8 bf[4];
#pragma unroll
            for (int nf = 0; nf < 4; ++nf)
                bf[nf] = *reinterpret_cast<const short8*>(
                    bbase + (size_t)((nf * 18 * 17 + icb * 4) * 8));
#pragma unroll
            for (int mf = 0; mf < 2; ++mf)
#pragma unroll
                for (int nf = 0; nf < 4; ++nf)
                    acc[mf][nf] = __builtin_amdgcn_mfma_f32_16x16x32_bf16(
                        A0[mf], bf[nf], acc[mf][nf], 0, 0, 0);
            if (k < 35) {
#pragma unroll
                for (int mf = 0; mf < 2; ++mf) {
                    A0[mf] = A1[mf];
                    if (k + 2 < 36) A1[mf] = A2[mf];
                }
            }
        }
    }

    const float* awb = aw4 + (size_t)b * 4 * HW_;
    float* outb = out + (size_t)b * 128 * HW_;
    const int head = qo;
#pragma unroll
    for (int mf = 0; mf < 2; ++mf) {
        const int oc0 = qo * 32 + mf * 16 + lk * 4;
#pragma unroll
        for (int nf = 0; nf < 4; ++nf) {
            int px = phalf * 64 + nf * 16 + lr;
            int hw = (by0 + (px >> 4)) * W_ + bx0 + (px & 15);
            float aw = awb[(size_t)head * HW_ + hw];
#pragma unroll
            for (int r = 0; r < 4; ++r) {
                int oc = oc0 + r;
                outb[(size_t)oc * HW_ + hw] = (acc[mf][nf][r] + tb[oc]) * aw;
            }
        }
    }
}

// ------------------------------------------------------------------
// K5 (fallback): fp32 direct conv
// ------------------------------------------------------------------
__global__ __launch_bounds__(256) void k5_conv(const float* __restrict__ x,
                                               const float* __restrict__ fac,
                                               const float* __restrict__ wt,
                                               const float* __restrict__ tb,
                                               const float* __restrict__ aw4,
                                               float* __restrict__ out) {
    __shared__ float ft[18][36];
    __shared__ float xs[16][18][36];
    __shared__ float wl[16][9][32];
    const int tx = threadIdx.x;
    const int ty = threadIdx.y;
    const int tid = ty * 32 + tx;
    const int bx0 = blockIdx.x * 32;
    const int by0 = blockIdx.y * 16;
    const int m = blockIdx.z & 3;
    const int b = blockIdx.z >> 2;

    for (int i = tid; i < 18 * 34; i += 256) {
        int r = i / 34, c = i - r * 34;
        int gy = by0 - 1 + r, gx = bx0 - 1 + c;
        bool in = (gy >= 0) && (gy < H_) && (gx < W_) && (gx >= 0);
        ft[r][c] = in ? fac[b * HW_ + gy * W_ + gx] : 0.f;
    }
    float acc0[32], acc1[32];
#pragma unroll
    for (int i = 0; i < 32; ++i) { acc0[i] = 0.f; acc1[i] = 0.f; }
    __syncthreads();

    for (int icc = 0; icc < 8; ++icc) {
        const int ic0 = icc * 16;
        for (int i = tid; i < 4608; i += 256) {
            int ic = i / 288; int rem = i - ic * 288;
            int tap = rem >> 5; int oc = rem & 31;
            wl[ic][tap][oc] = wt[((ic0 + ic) * 9 + tap) * 128 + m * 32 + oc];
        }
        for (int i = tid; i < 16 * 612; i += 256) {
            int ic = i / 612; int j = i - ic * 612;
            int r = j / 34; int c = j - r * 34;
            int gy = by0 - 1 + r, gx = bx0 - 1 + c;
            int gyc = min(max(gy, 0), H_ - 1), gxc = min(max(gx, 0), W_ - 1);
            xs[ic][r][c] = x[((size_t)(b * C1_ + ic0 + ic)) * HW_ + gyc * W_ + gxc] * ft[r][c];
        }
        __syncthreads();
        for (int ic = 0; ic < 16; ++ic) {
#pragma unroll
            for (int ky = 0; ky < 3; ++ky) {
#pragma unroll
                for (int kx = 0; kx < 3; ++kx) {
                    float xv0 = xs[ic][ty + ky][tx + kx];
                    float xv1 = xs[ic][ty + 8 + ky][tx + kx];
                    const float4* wp = (const float4*)&wl[ic][ky * 3 + kx][0];
#pragma unroll
                    for (int o4 = 0; o4 < 8; ++o4) {
                        float4 wv = wp[o4];
                        acc0[o4 * 4 + 0] += xv0 * wv.x; acc0[o4 * 4 + 1] += xv0 * wv.y;
                        acc0[o4 * 4 + 2] += xv0 * wv.z; acc0[o4 * 4 + 3] += xv0 * wv.w;
                        acc1[o4 * 4 + 0] += xv1 * wv.x; acc1[o4 * 4 + 1] += xv1 * wv.y;
                        acc1[o4 * 4 + 2] += xv1 * wv.z; acc1[o4 * 4 + 3] += xv1 * wv.w;
                    }
                }
            }
        }
        __syncthreads();
    }

    const int hw0 = (by0 + ty) * W_ + bx0 + tx;
    const int hw1 = (by0 + ty + 8) * W_ + bx0 + tx;
    const float aw0 = aw4[((size_t)(b * 4 + m)) * HW_ + hw0];
    const float aw1 = aw4[((size_t)(b * 4 + m)) * HW_ + hw1];
    float* ob = out + ((size_t)(b * C1_ + m * 32)) * HW_;
#pragma unroll
    for (int oc = 0; oc < 32; ++oc) {
        float t = tb[m * 32 + oc];
        ob[oc * HW_ + hw0] = (acc0[oc] + t) * aw0;
        ob[oc * HW_ + hw1] = (acc1[oc] + t) * aw1;
    }
}

// ------------------------------------------------------------------
extern "C" void kernel_launch(void* const* d_in, const int* in_sizes, int n_in,
                              void* d_out, int out_size, void* d_ws, size_t ws_size,
                              hipStream_t stream) {
    const float* x        = (const float*)d_in[0];
    const float* guide    = (const float*)d_in[1];
    const float* w_gm1    = (const float*)d_in[2];
    const float* b_gm1    = (const float*)d_in[3];
    const float* w_gm2    = (const float*)d_in[4];
    const float* b_gm2    = (const float*)d_in[5];
    // d_in[6..10]: w_qkv, w_ge1, b_ge1, w_ge2, b_ge2 -- mathematically unused
    const float* w_gl     = (const float*)d_in[11];
    const float* b_gl     = (const float*)d_in[12];
    const float* attn_bias= (const float*)d_in[13];
    const float* w_proj   = (const float*)d_in[14];
    const float* bn_gamma = (const float*)d_in[15];
    const float* bn_beta  = (const float*)d_in[16];
    const float* bn_mean  = (const float*)d_in[17];
    const float* bn_var   = (const float*)d_in[18];

    char* wsb = (char*)d_ws;
    float* fac = (float*)(wsb + OFF_FAC);
    float* imp = (float*)(wsb + OFF_IMP);
    float* aw4 = (float*)(wsb + OFF_AW4);
    float* g   = (float*)(wsb + OFF_G);
    float* tb  = (float*)(wsb + OFF_TB);
    float* wt  = (float*)(wsb + OFF_WT);
    unsigned short* wpk = (unsigned short*)(wsb + OFF_WPK);
    unsigned short* xh  = (unsigned short*)(wsb + OFF_XH);

    float* out0 = (float*)d_out;
    float* out1 = (float*)d_out + (size_t)B_ * C1_ * HW_;

    const bool fast = (ws_size >= WS_NEED_FAST);

    k_prep<<<dim3(1280), dim3(256), 0, stream>>>(w_proj, bn_gamma, bn_beta, bn_mean,
                                                 bn_var, guide, w_gl, b_gl,
                                                 wt, tb, wpk, g);
    if (fast) {
        k1a_convert<<<dim3(100, 8), dim3(512), 0, stream>>>(x, imp, xh);
        k2_topk<<<dim3(8), dim3(1024), 0, stream>>>(imp, fac, 1);
        k4m2_scores<<<dim3(200, 8), dim3(256), 0, stream>>>(xh, g, w_gm1, b_gm1,
                                                            w_gm2, b_gm2, attn_bias,
                                                            fac, aw4, out1);
        k5_mfma<<<dim3(10, 20, 8), dim3(512), 0, stream>>>(xh, fac, wpk, tb, aw4, out0);
    } else {
        k1_mod<<<dim3(50, 8), dim3(256), 0, stream>>>(x, w_gm1, b_gm1, w_gm2, b_gm2,
                                                      fac, imp);
        k2_topk<<<dim3(8), dim3(1024), 0, stream>>>(imp, fac, 0);
        k4_aw<<<dim3(100, 8), dim3(256), 0, stream>>>(x, fac, g, attn_bias, aw4, out1);
        k5_conv<<<dim3(5, 10, B_ * 4), dim3(32, 8), 0, stream>>>(x, fac, wt, tb, aw4, out0);
    }
}

// Round 17
// 185.138 us; speedup vs baseline: 1.1041x; 1.0620x over previous
//
#include <hip/hip_runtime.h>
#include <hip/hip_bf16.h>
#include <math.h>

// Sizes (fixed by the reference)
#define B_   8
#define C1_  128
#define H_   160
#define W_   160
#define HW_  25600         // 160*160
#define NSEL_ 64
#define BONUS_ 4.6875e-4f  // 0.1*0.3/64

typedef __attribute__((ext_vector_type(8))) unsigned short ushort8;
typedef __attribute__((ext_vector_type(8))) short short8;
typedef __attribute__((ext_vector_type(4))) float f32x4;

// ---------------- workspace layout (byte offsets) ----------------
#define OFF_FAC 0
#define OFF_IMP 819200
#define OFF_AW4 1638400
#define OFF_G   4915200
#define OFF_TB  5046272
#define OFF_WT  5046784
#define OFF_WPK 5636608
#define OFF_XH  5931520
#define WS_NEED_FAST 58360320ULL
// xh holds bf16(x) (unscaled); k5 applies fac during staging.
// mx4[b][hw][4] f32 lives in d_out[0..3.3MB] as scratch (k14 writes, k2 reads,
// k5 overwrites).  fac: k14 writes 1+0.0175*fm; k2 adds BONUS to top-64 and
// exactly recomputes their aw4/aw_single from mx4.

__device__ __forceinline__ float sigmoidf_(float v) {
    return 1.0f / (1.0f + expf(-v));
}
__device__ __forceinline__ unsigned short f2bf(float f) {  // RNE f32->bf16
    unsigned u = __float_as_uint(f);
    return (unsigned short)((u + 0x7fffu + ((u >> 16) & 1u)) >> 16);
}
__device__ __forceinline__ float bf2f(unsigned short h) {
    return __uint_as_float(((unsigned)h) << 16);
}

// ------------------------------------------------------------------
// K_PREP: fused k0_wt + k0b_pack + k3_guide (independent prep work).
// blocks [0,576): BN-folded fp32 wt + tb;  [576,1152): MFMA-packed wpk;
// [1152,1280): guide GEMM g (2 rows per block).  grid 1280 x 256.
// ------------------------------------------------------------------
__global__ __launch_bounds__(256) void k_prep(const float* __restrict__ wp,
                                              const float* __restrict__ gamma,
                                              const float* __restrict__ beta,
                                              const float* __restrict__ mean,
                                              const float* __restrict__ var,
                                              const float* __restrict__ guide,
                                              const float* __restrict__ w_gl,
                                              const float* __restrict__ b_gl,
                                              float* __restrict__ wt,
                                              float* __restrict__ tb,
                                              unsigned short* __restrict__ wpk,
                                              float* __restrict__ g) {
    const int blk = blockIdx.x;
    const int tid = threadIdx.x;
    if (blk < 576) {
        int i = blk * 256 + tid;
        if (i < 128) {
            float s = gamma[i] * rsqrtf(var[i] + 1e-5f);
            tb[i] = beta[i] - mean[i] * s;
        }
        if (i < 147456) {
            int o = i & 127, it = i >> 7;
            float s = gamma[o] * rsqrtf(var[o] + 1e-5f);
            wt[i] = wp[o * 1152 + it] * s;
        }
    } else if (blk < 1152) {
        int idx = (blk - 576) * 256 + tid;
        if (idx < 147456) {
            int j = idx & 7, l = (idx >> 3) & 63, f = idx >> 9;
            int kstep = f >> 3, mblk = f & 7;
            int tap = kstep >> 2, icb = kstep & 3;
            int oc = mblk * 16 + (l & 15);
            int ic = icb * 32 + ((l >> 4) << 3) + j;
            float s = gamma[oc] * rsqrtf(var[oc] + 1e-5f);
            wpk[idx] = f2bf(wp[oc * 1152 + ic * 9 + tap] * s);
        }
    } else {
        __shared__ float gr[2][512];
        const int half = tid >> 7, t = tid & 127;
        const int bn = (blk - 1152) * 2 + half;
        for (int i = t; i < 512; i += 128) gr[half][i] = guide[bn * 512 + i];
        __syncthreads();
        const float4* w4 = (const float4*)(w_gl + (size_t)t * 512);
        const float4* g4 = (const float4*)gr[half];
        float acc = b_gl[t];
        for (int k = 0; k < 128; ++k) {
            float4 w = w4[k]; float4 v = g4[k];
            acc += w.x * v.x + w.y * v.y + w.z * v.z + w.w * v.w;
        }
        g[bn * 128 + t] = acc;
    }
}

// ------------------------------------------------------------------
// K14 (fast): fused convert + scores + MLP per 128-px tile.
//  phase 1: read x (NCHW fp32, reg-transpose), -> bf16 xs (swizzled LDS)
//           + xh (global, for k5) + imp (LDS-reduced mean|x|)
//  phase 2: MFMA scores mx[m] + MLP fm -> fac = 1+0.0175*fm (no bonus),
//           mx4 scratch write, aw4/aw_single with this fac.
// grid (200, 8) x 256.  LDS 32KB xs + 4KB red.
// ------------------------------------------------------------------
__global__ __launch_bounds__(256) void k14_fused(const float* __restrict__ x,
                                                 const float* __restrict__ g,
                                                 const float* __restrict__ w_gm1,
                                                 const float* __restrict__ b_gm1,
                                                 const float* __restrict__ w_gm2,
                                                 const float* __restrict__ b_gm2,
                                                 const float* __restrict__ attn_bias,
                                                 float* __restrict__ imp,
                                                 float* __restrict__ fac,
                                                 float* __restrict__ aw4,
                                                 float* __restrict__ aw_single,
                                                 float* __restrict__ mx4,
                                                 unsigned short* __restrict__ xh) {
    __shared__ unsigned short xs[128 * 128];   // [row][slot]; slot s holds granule s^(row&7)
    __shared__ float red[8][128];
    const int tid = threadIdx.x;
    const int px0 = blockIdx.x * 128;
    const int b = blockIdx.y;

    // ---- phase 1: convert.  thread: cg = tid>>5 (16 ch), pgl = tid&31 (4 px) ----
    {
        const int cg = tid >> 5, pgl = tid & 31;
        const int pxl = pgl * 4;
        const float* xb = x + (size_t)b * C1_ * HW_ + px0 + pxl;
        unsigned short* xrb = xh + ((size_t)(b * HW_ + px0 + pxl)) * 128 + cg * 16;

        float sab0 = 0.f, sab1 = 0.f, sab2 = 0.f, sab3 = 0.f;
        ushort8 v0[2], v1[2], v2[2], v3[2];
#pragma unroll
        for (int j = 0; j < 16; ++j) {
            float4 xv = *reinterpret_cast<const float4*>(xb + (size_t)(cg * 16 + j) * HW_);
            sab0 += fabsf(xv.x); sab1 += fabsf(xv.y);
            sab2 += fabsf(xv.z); sab3 += fabsf(xv.w);
            const int q = j >> 3, jj = j & 7;
            v0[q][jj] = f2bf(xv.x); v1[q][jj] = f2bf(xv.y);
            v2[q][jj] = f2bf(xv.z); v3[q][jj] = f2bf(xv.w);
        }
        // global xh write (k5 consumes): 2 x 16B per px, contiguous 32B
#pragma unroll
        for (int q = 0; q < 2; ++q) {
            *reinterpret_cast<ushort8*>(xrb + 0 * 128 + q * 8) = v0[q];
            *reinterpret_cast<ushort8*>(xrb + 1 * 128 + q * 8) = v1[q];
            *reinterpret_cast<ushort8*>(xrb + 2 * 128 + q * 8) = v2[q];
            *reinterpret_cast<ushort8*>(xrb + 3 * 128 + q * 8) = v3[q];
        }
        // LDS write, swizzled: slot = granule ^ (row&7)
#pragma unroll
        for (int q = 0; q < 2; ++q) {
            const int g2 = cg * 2 + q;
            int s0 = g2 ^ ((pxl + 0) & 7), s1 = g2 ^ ((pxl + 1) & 7);
            int s2 = g2 ^ ((pxl + 2) & 7), s3 = g2 ^ ((pxl + 3) & 7);
            *reinterpret_cast<ushort8*>(xs + (size_t)((pxl + 0) * 16 + s0) * 8) = v0[q];
            *reinterpret_cast<ushort8*>(xs + (size_t)((pxl + 1) * 16 + s1) * 8) = v1[q];
            *reinterpret_cast<ushort8*>(xs + (size_t)((pxl + 2) * 16 + s2) * 8) = v2[q];
            *reinterpret_cast<ushort8*>(xs + (size_t)((pxl + 3) * 16 + s3) * 8) = v3[q];
        }
        red[cg][pxl + 0] = sab0; red[cg][pxl + 1] = sab1;
        red[cg][pxl + 2] = sab2; red[cg][pxl + 3] = sab3;
    }
    __syncthreads();
    if (tid < 128) {
        float s = 0.f;
#pragma unroll
        for (int gg = 0; gg < 8; ++gg) s += red[gg][tid];
        imp[b * HW_ + px0 + tid] = s * (1.f / 128.f);
    }

    // ---- phase 2: scores + MLP (verified k4m2 structure; xs layout identical) ----
    const int l = tid & 63, w = tid >> 6;
    const int lr = l & 15, lk = l >> 4;

    short8 afr[4][2];
#pragma unroll
    for (int m = 0; m < 4; ++m)
#pragma unroll
        for (int nb = 0; nb < 2; ++nb) {
            const float* gp = g + (size_t)b * 4096 + (nb * 16 + lr) * 128
                              + m * 32 + (lk << 3);
            float4 g0 = *reinterpret_cast<const float4*>(gp);
            float4 g1 = *reinterpret_cast<const float4*>(gp + 4);
            short8 a;
            a[0] = (short)f2bf(g0.x); a[1] = (short)f2bf(g0.y);
            a[2] = (short)f2bf(g0.z); a[3] = (short)f2bf(g0.w);
            a[4] = (short)f2bf(g1.x); a[5] = (short)f2bf(g1.y);
            a[6] = (short)f2bf(g1.z); a[7] = (short)f2bf(g1.w);
            afr[m][nb] = a;
        }

    short8 w1f[2][4];
#pragma unroll
    for (int ob = 0; ob < 2; ++ob)
#pragma unroll
        for (int kb = 0; kb < 4; ++kb) {
            const float* wp = w_gm1 + (size_t)(ob * 16 + lr) * 128 + kb * 32 + (lk << 3);
            float4 g0 = *reinterpret_cast<const float4*>(wp);
            float4 g1 = *reinterpret_cast<const float4*>(wp + 4);
            short8 a;
            a[0] = (short)f2bf(g0.x); a[1] = (short)f2bf(g0.y);
            a[2] = (short)f2bf(g0.z); a[3] = (short)f2bf(g0.w);
            a[4] = (short)f2bf(g1.x); a[5] = (short)f2bf(g1.y);
            a[6] = (short)f2bf(g1.z); a[7] = (short)f2bf(g1.w);
            w1f[ob][kb] = a;
        }

    float b1r[8], w2r[4][8];
#pragma unroll
    for (int r = 0; r < 4; ++r) {
        b1r[r] = b_gm1[lk * 4 + r];
        b1r[4 + r] = b_gm1[16 + lk * 4 + r];
    }
#pragma unroll
    for (int m = 0; m < 4; ++m)
#pragma unroll
        for (int r = 0; r < 4; ++r) {
            w2r[m][r] = w_gm2[m * 32 + lk * 4 + r];
            w2r[m][4 + r] = w_gm2[m * 32 + 16 + lk * 4 + r];
        }
    const float b20 = b_gm2[0], b21 = b_gm2[1], b22 = b_gm2[2], b23 = b_gm2[3];
    const float ab0 = attn_bias[0], ab1 = attn_bias[1];
    const float ab2 = attn_bias[2], ab3 = attn_bias[3];

#pragma unroll
    for (int pxb = 0; pxb < 2; ++pxb) {
        const int px = (w * 2 + pxb) * 16 + lr;
        float mr[4];
        f32x4 h0{0.f, 0.f, 0.f, 0.f}, h1{0.f, 0.f, 0.f, 0.f};
#pragma unroll
        for (int m = 0; m < 4; ++m) {
            int gl = (m * 4 + lk) ^ (px & 7);
            short8 bf = *reinterpret_cast<const short8*>(xs + (size_t)px * 128 + gl * 8);
            f32x4 a0{0.f, 0.f, 0.f, 0.f}, a1{0.f, 0.f, 0.f, 0.f};
            a0 = __builtin_amdgcn_mfma_f32_16x16x32_bf16(afr[m][0], bf, a0, 0, 0, 0);
            a1 = __builtin_amdgcn_mfma_f32_16x16x32_bf16(afr[m][1], bf, a1, 0, 0, 0);
            h0 = __builtin_amdgcn_mfma_f32_16x16x32_bf16(w1f[0][m], bf, h0, 0, 0, 0);
            h1 = __builtin_amdgcn_mfma_f32_16x16x32_bf16(w1f[1][m], bf, h1, 0, 0, 0);
            float v = fmaxf(fmaxf(fmaxf(a0[0], a0[1]), fmaxf(a0[2], a0[3])),
                            fmaxf(fmaxf(a1[0], a1[1]), fmaxf(a1[2], a1[3])));
            v = fmaxf(v, __shfl_xor(v, 16));
            v = fmaxf(v, __shfl_xor(v, 32));
            mr[m] = v;
        }
        float s0 = b20, s1 = b21, s2 = b22, s3 = b23;
#pragma unroll
        for (int r = 0; r < 4; ++r) {
            float hv0 = fmaxf(h0[r] + b1r[r], 0.f);
            float hv1 = fmaxf(h1[r] + b1r[4 + r], 0.f);
            s0 += w2r[0][r] * hv0 + w2r[0][4 + r] * hv1;
            s1 += w2r[1][r] * hv0 + w2r[1][4 + r] * hv1;
            s2 += w2r[2][r] * hv0 + w2r[2][4 + r] * hv1;
            s3 += w2r[3][r] * hv0 + w2r[3][4 + r] * hv1;
        }
        s0 += __shfl_xor(s0, 16); s0 += __shfl_xor(s0, 32);
        s1 += __shfl_xor(s1, 16); s1 += __shfl_xor(s1, 32);
        s2 += __shfl_xor(s2, 16); s2 += __shfl_xor(s2, 32);
        s3 += __shfl_xor(s3, 16); s3 += __shfl_xor(s3, 32);
        float fm = sigmoidf_(s0) + sigmoidf_(s1) + sigmoidf_(s2) + sigmoidf_(s3);
        if (l < 16) {
            int hw = px0 + (w * 2 + pxb) * 16 + l;
            float fv = 1.f + 0.0175f * fm;   // 0.07 * 0.25; bonus added by k2
            fac[b * HW_ + hw] = fv;
            float4 o; o.x = mr[0]; o.y = mr[1]; o.z = mr[2]; o.w = mr[3];
            *reinterpret_cast<float4*>(mx4 + (size_t)(b * HW_ + hw) * 4) = o;
            float sc = fv * 0.17677669529663687f;
            float a0 = sigmoidf_(mr[0] * sc + ab0);
            float a1 = sigmoidf_(mr[1] * sc + ab1);
            float a2 = sigmoidf_(mr[2] * sc + ab2);
            float a3 = sigmoidf_(mr[3] * sc + ab3);
            aw4[((size_t)(b * 4 + 0)) * HW_ + hw] = a0;
            aw4[((size_t)(b * 4 + 1)) * HW_ + hw] = a1;
            aw4[((size_t)(b * 4 + 2)) * HW_ + hw] = a2;
            aw4[((size_t)(b * 4 + 3)) * HW_ + hw] = a3;
            aw_single[b * HW_ + hw] = (a0 + a1 + a2 + a3) * 0.25f;
        }
    }
}

// ------------------------------------------------------------------
// K1 (fallback): fused MLP + imp (no xh write).
// grid (50, 8) x 256.
// ------------------------------------------------------------------
__global__ __launch_bounds__(256) void k1_mod(const float* __restrict__ x,
                                              const float* __restrict__ w_gm1,
                                              const float* __restrict__ b_gm1,
                                              const float* __restrict__ w_gm2,
                                              const float* __restrict__ b_gm2,
                                              float* __restrict__ fac,
                                              float* __restrict__ imp) {
    __shared__ float4 w1t[128 * 8];
    __shared__ float  b1s[32];
    __shared__ float  w2s[128];
    __shared__ float  b2s[4];
    const int tid = threadIdx.x;
    for (int i = tid; i < 4096; i += 256) {
        int j = i >> 7, c = i & 127;
        ((float*)w1t)[c * 32 + j] = w_gm1[i];
    }
    if (tid < 32) b1s[tid] = b_gm1[tid];
    if (tid < 128) w2s[tid] = w_gm2[tid];
    if (tid < 4) b2s[tid] = b_gm2[tid];
    __syncthreads();

    const int hw0 = blockIdx.x * 512 + tid * 2;
    const int b = blockIdx.y;
    const float* xb = x + (size_t)b * C1_ * HW_ + hw0;

    float h[2][32];
#pragma unroll
    for (int j = 0; j < 32; ++j) { h[0][j] = 0.f; h[1][j] = 0.f; }
    float sab0 = 0.f, sab1 = 0.f;
    for (int c8 = 0; c8 < 16; ++c8) {
#pragma unroll
        for (int k = 0; k < 8; ++k) {
            int c = c8 * 8 + k;
            float2 xv = *reinterpret_cast<const float2*>(xb + (size_t)c * HW_);
            sab0 += fabsf(xv.x);
            sab1 += fabsf(xv.y);
            const float4* wr = &w1t[c * 8];
#pragma unroll
            for (int j4 = 0; j4 < 8; ++j4) {
                float4 w = wr[j4];
                h[0][j4 * 4 + 0] += xv.x * w.x; h[0][j4 * 4 + 1] += xv.x * w.y;
                h[0][j4 * 4 + 2] += xv.x * w.z; h[0][j4 * 4 + 3] += xv.x * w.w;
                h[1][j4 * 4 + 0] += xv.y * w.x; h[1][j4 * 4 + 1] += xv.y * w.y;
                h[1][j4 * 4 + 2] += xv.y * w.z; h[1][j4 * 4 + 3] += xv.y * w.w;
            }
        }
    }
#pragma unroll
    for (int p = 0; p < 2; ++p) {
        float fm = 0.f;
#pragma unroll
        for (int j = 0; j < 32; ++j) h[p][j] = fmaxf(h[p][j] + b1s[j], 0.f);
#pragma unroll
        for (int m = 0; m < 4; ++m) {
            float s = b2s[m];
#pragma unroll
            for (int j = 0; j < 32; ++j) s += w2s[m * 32 + j] * h[p][j];
            fm += sigmoidf_(s);
        }
        fac[b * HW_ + hw0 + p] = 1.f + 0.07f * (fm * 0.25f);
        imp[b * HW_ + hw0 + p] = (p == 0 ? sab0 : sab1) * (1.f / 128.f);
    }
}

// ------------------------------------------------------------------
// K2: exact top-64 per batch (radix binary search on float bits).
// mode 1 (fast): fac[idx] += BONUS and exactly recompute aw from mx4.
// mode 0 (fallback): fac[idx] += BONUS only.
// ------------------------------------------------------------------
__device__ __forceinline__ int blockReduceSum1024(int v, int* red, int tid) {
#pragma unroll
    for (int off = 32; off >= 1; off >>= 1) v += __shfl_down(v, off);
    if ((tid & 63) == 0) red[tid >> 6] = v;
    __syncthreads();
    if (tid < 64) {
        int s = (tid < 16) ? red[tid] : 0;
#pragma unroll
        for (int off = 8; off >= 1; off >>= 1) s += __shfl_down(s, off);
        if (tid == 0) red[16] = s;
    }
    __syncthreads();
    int r = red[16];
    __syncthreads();
    return r;
}

__device__ __forceinline__ void bump_px2(float* __restrict__ fac,
                                         const float* __restrict__ mx4,
                                         float* __restrict__ aw4,
                                         float* __restrict__ aw_single,
                                         const float* __restrict__ attn_bias,
                                         int b, int idx, int mode) {
    float fv = fac[b * HW_ + idx] + BONUS_;
    fac[b * HW_ + idx] = fv;
    if (mode) {
        float4 mv = *reinterpret_cast<const float4*>(mx4 + (size_t)(b * HW_ + idx) * 4);
        float sc = fv * 0.17677669529663687f;
        float a0 = sigmoidf_(mv.x * sc + attn_bias[0]);
        float a1 = sigmoidf_(mv.y * sc + attn_bias[1]);
        float a2 = sigmoidf_(mv.z * sc + attn_bias[2]);
        float a3 = sigmoidf_(mv.w * sc + attn_bias[3]);
        aw4[((size_t)(b * 4 + 0)) * HW_ + idx] = a0;
        aw4[((size_t)(b * 4 + 1)) * HW_ + idx] = a1;
        aw4[((size_t)(b * 4 + 2)) * HW_ + idx] = a2;
        aw4[((size_t)(b * 4 + 3)) * HW_ + idx] = a3;
        aw_single[b * HW_ + idx] = (a0 + a1 + a2 + a3) * 0.25f;
    }
}

__global__ __launch_bounds__(1024) void k2_topk(const float* __restrict__ imp,
                                                float* __restrict__ fac,
                                                const float* __restrict__ mx4,
                                                float* __restrict__ aw4,
                                                float* __restrict__ aw_single,
                                                const float* __restrict__ attn_bias,
                                                int mode) {
    __shared__ int red[17];
    __shared__ int claimed;
    const int tid = threadIdx.x;
    const int b = blockIdx.x;
    unsigned u[25];
#pragma unroll
    for (int i = 0; i < 25; ++i)
        u[i] = __float_as_uint(imp[b * HW_ + i * 1024 + tid]);

    unsigned cur = 0u;
    for (int bit = 30; bit >= 0; --bit) {
        unsigned cand = cur | (1u << bit);
        int c = 0;
#pragma unroll
        for (int i = 0; i < 25; ++i) c += (u[i] >= cand) ? 1 : 0;
        int tot = blockReduceSum1024(c, red, tid);
        if (tot >= NSEL_) cur = cand;
    }
    int cg = 0;
#pragma unroll
    for (int i = 0; i < 25; ++i) cg += (u[i] > cur) ? 1 : 0;
    int tot_gt = blockReduceSum1024(cg, red, tid);
    int need = NSEL_ - tot_gt;
    if (tid == 0) claimed = 0;
    __syncthreads();
#pragma unroll
    for (int i = 0; i < 25; ++i) {
        int idx = i * 1024 + tid;
        if (u[i] > cur) {
            bump_px2(fac, mx4, aw4, aw_single, attn_bias, b, idx, mode);
        } else if (u[i] == cur) {
            int c = atomicAdd(&claimed, 1);
            if (c < need) bump_px2(fac, mx4, aw4, aw_single, attn_bias, b, idx, mode);
        }
    }
}

// ------------------------------------------------------------------
// K4 (fallback): aw from fp32 NCHW x.
// ------------------------------------------------------------------
__global__ __launch_bounds__(256) void k4_aw(const float* __restrict__ x,
                                             const float* __restrict__ fac,
                                             const float* __restrict__ g,
                                             const float* __restrict__ attn_bias,
                                             float* __restrict__ aw4,
                                             float* __restrict__ aw_single) {
    __shared__ float gl[4096];
    __shared__ float biass[4];
    const int tid = threadIdx.x;
    const int b = blockIdx.y;
    for (int i = tid; i < 4096; i += 256) {
        int n = i >> 7, e = i & 127;
        gl[e * 32 + n] = g[b * 4096 + i];
    }
    if (tid < 4) biass[tid] = attn_bias[tid];
    __syncthreads();
    const int hw = blockIdx.x * 256 + tid;
    const float facv = fac[b * HW_ + hw];
    const float* xb = x + (size_t)b * C1_ * HW_ + hw;
    float asum = 0.f;
#pragma unroll
    for (int m = 0; m < 4; ++m) {
        float acc[32];
#pragma unroll
        for (int n = 0; n < 32; ++n) acc[n] = 0.f;
        for (int c = 0; c < 32; ++c) {
            float xv = xb[(m * 32 + c) * HW_] * facv;
            const float4* grow = (const float4*)&gl[(m * 32 + c) * 32];
#pragma unroll
            for (int n4 = 0; n4 < 8; ++n4) {
                float4 gv = grow[n4];
                acc[n4 * 4 + 0] += xv * gv.x; acc[n4 * 4 + 1] += xv * gv.y;
                acc[n4 * 4 + 2] += xv * gv.z; acc[n4 * 4 + 3] += xv * gv.w;
            }
        }
        float mxv = acc[0];
#pragma unroll
        for (int n = 1; n < 32; ++n) mxv = fmaxf(mxv, acc[n]);
        float awv = sigmoidf_(mxv * 0.17677669529663687f + biass[m]);
        aw4[((size_t)(b * 4 + m)) * HW_ + hw] = awv;
        asum += awv;
    }
    aw_single[b * HW_ + hw] = asum * 0.25f;
}

// ------------------------------------------------------------------
// K5 (fast, v8): implicit-GEMM MFMA conv, 512 threads / 8 waves per
// block (128px x 128oc tile; each wave = 32oc x 64px).  R13/R14-verified.
// grid (10, 20, 8), block 512.  LDS 48960 B.
// ------------------------------------------------------------------
__global__ __launch_bounds__(512, 4) void k5_mfma(const unsigned short* __restrict__ xh,
                                                  const float* __restrict__ fac,
                                                  const unsigned short* __restrict__ wpk,
                                                  const float* __restrict__ tb,
                                                  const float* __restrict__ aw4,
                                                  float* __restrict__ out) {
    __shared__ unsigned short xs[180 * 17 * 8];
    const int tid = threadIdx.x;
    const int l = tid & 63, w = tid >> 6;      // w: 0..7
    const int bx0 = blockIdx.x * 16;
    const int by0 = blockIdx.y * 8;
    const int b   = blockIdx.z;

    for (int i = tid; i < 2880; i += 512) {
        int gg = i & 15, pc = i >> 4;
        int hc = pc % 18, hr = pc / 18;
        int gy = by0 - 1 + hr, gx = bx0 - 1 + hc;
        ushort8 v;
#pragma unroll
        for (int k = 0; k < 8; ++k) v[k] = 0;
        if (gy >= 0 && gy < H_ && gx >= 0 && gx < W_) {
            int hw = gy * W_ + gx;
            v = *reinterpret_cast<const ushort8*>(xh + ((size_t)b * HW_ + hw) * 128 + gg * 8);
            float fv = fac[b * HW_ + hw];
#pragma unroll
            for (int k = 0; k < 8; ++k) v[k] = f2bf(bf2f(v[k]) * fv);
        }
        *reinterpret_cast<ushort8*>(xs + (size_t)(pc * 17 + gg) * 8) = v;
    }
    __syncthreads();

    const int qo = w >> 1;        // oc quarter: 32 oc (= mblks qo*2, qo*2+1)
    const int phalf = w & 1;      // px half: 64 px
    const int lr = l & 15, lk = l >> 4;

    f32x4 acc[2][4];
#pragma unroll
    for (int mf = 0; mf < 2; ++mf)
#pragma unroll
        for (int nf = 0; nf < 4; ++nf)
#pragma unroll
            for (int r = 0; r < 4; ++r) acc[mf][nf][r] = 0.f;

    const unsigned short* wlane = wpk + (size_t)(qo * 2) * 512 + (size_t)l * 8;
    const unsigned short* xbase = xs + (size_t)((phalf * 4 * 18 + lr) * 17 + lk) * 8;

    short8 A0[2], A1[2];
#pragma unroll
    for (int mf = 0; mf < 2; ++mf) {
        A0[mf] = *reinterpret_cast<const short8*>(wlane + mf * 512);
        A1[mf] = *reinterpret_cast<const short8*>(wlane + 4096 + mf * 512);
    }

#pragma unroll 1
    for (int tap = 0; tap < 9; ++tap) {
        const int dy = (tap >= 6) ? 2 : (tap >= 3 ? 1 : 0);
        const int dx = tap - dy * 3;
        const unsigned short* bbase = xbase + (size_t)(((dy * 18 + dx) * 17) * 8);
        const unsigned short* wpre = wlane + (size_t)(tap * 4 + 2) * 4096;
#pragma unroll
        for (int icb = 0; icb < 4; ++icb) {
            const int k = tap * 4 + icb;
            short8 A2[2];
            if (k + 2 < 36) {
#pragma unroll
                for (int mf = 0; mf < 2; ++mf)
                    A2[mf] = *reinterpret_cast<const short8*>(wpre + (size_t)icb * 4096 + mf * 512);
            }
            short8 bf[4];
#pragma unroll
            for (int nf = 0; nf < 4; ++nf)
                bf[nf] = *reinterpret_cast<const short8*>(
                    bbase + (size_t)((nf * 18 * 17 + icb * 4) * 8));
#pragma unroll
            for (int mf = 0; mf < 2; ++mf)
#pragma unroll
                for (int nf = 0; nf < 4; ++nf)
                    acc[mf][nf] = __builtin_amdgcn_mfma_f32_16x16x32_bf16(
                        A0[mf], bf[nf], acc[mf][nf], 0, 0, 0);
            if (k < 35) {
#pragma unroll
                for (int mf = 0; mf < 2; ++mf) {
                    A0[mf] = A1[mf];
                    if (k + 2 < 36) A1[mf] = A2[mf];
                }
            }
        }
    }

    const float* awb = aw4 + (size_t)b * 4 * HW_;
    float* outb = out + (size_t)b * 128 * HW_;
    const int head = qo;
#pragma unroll
    for (int mf = 0; mf < 2; ++mf) {
        const int oc0 = qo * 32 + mf * 16 + lk * 4;
#pragma unroll
        for (int nf = 0; nf < 4; ++nf) {
            int px = phalf * 64 + nf * 16 + lr;
            int hw = (by0 + (px >> 4)) * W_ + bx0 + (px & 15);
            float aw = awb[(size_t)head * HW_ + hw];
#pragma unroll
            for (int r = 0; r < 4; ++r) {
                int oc = oc0 + r;
                outb[(size_t)oc * HW_ + hw] = (acc[mf][nf][r] + tb[oc]) * aw;
            }
        }
    }
}

// ------------------------------------------------------------------
// K5 (fallback): fp32 direct conv
// ------------------------------------------------------------------
__global__ __launch_bounds__(256) void k5_conv(const float* __restrict__ x,
                                               const float* __restrict__ fac,
                                               const float* __restrict__ wt,
                                               const float* __restrict__ tb,
                                               const float* __restrict__ aw4,
                                               float* __restrict__ out) {
    __shared__ float ft[18][36];
    __shared__ float xs[16][18][36];
    __shared__ float wl[16][9][32];
    const int tx = threadIdx.x;
    const int ty = threadIdx.y;
    const int tid = ty * 32 + tx;
    const int bx0 = blockIdx.x * 32;
    const int by0 = blockIdx.y * 16;
    const int m = blockIdx.z & 3;
    const int b = blockIdx.z >> 2;

    for (int i = tid; i < 18 * 34; i += 256) {
        int r = i / 34, c = i - r * 34;
        int gy = by0 - 1 + r, gx = bx0 - 1 + c;
        bool in = (gy >= 0) && (gy < H_) && (gx < W_) && (gx >= 0);
        ft[r][c] = in ? fac[b * HW_ + gy * W_ + gx] : 0.f;
    }
    float acc0[32], acc1[32];
#pragma unroll
    for (int i = 0; i < 32; ++i) { acc0[i] = 0.f; acc1[i] = 0.f; }
    __syncthreads();

    for (int icc = 0; icc < 8; ++icc) {
        const int ic0 = icc * 16;
        for (int i = tid; i < 4608; i += 256) {
            int ic = i / 288; int rem = i - ic * 288;
            int tap = rem >> 5; int oc = rem & 31;
            wl[ic][tap][oc] = wt[((ic0 + ic) * 9 + tap) * 128 + m * 32 + oc];
        }
        for (int i = tid; i < 16 * 612; i += 256) {
            int ic = i / 612; int j = i - ic * 612;
            int r = j / 34; int c = j - r * 34;
            int gy = by0 - 1 + r, gx = bx0 - 1 + c;
            int gyc = min(max(gy, 0), H_ - 1), gxc = min(max(gx, 0), W_ - 1);
            xs[ic][r][c] = x[((size_t)(b * C1_ + ic0 + ic)) * HW_ + gyc * W_ + gxc] * ft[r][c];
        }
        __syncthreads();
        for (int ic = 0; ic < 16; ++ic) {
#pragma unroll
            for (int ky = 0; ky < 3; ++ky) {
#pragma unroll
                for (int kx = 0; kx < 3; ++kx) {
                    float xv0 = xs[ic][ty + ky][tx + kx];
                    float xv1 = xs[ic][ty + 8 + ky][tx + kx];
                    const float4* wp = (const float4*)&wl[ic][ky * 3 + kx][0];
#pragma unroll
                    for (int o4 = 0; o4 < 8; ++o4) {
                        float4 wv = wp[o4];
                        acc0[o4 * 4 + 0] += xv0 * wv.x; acc0[o4 * 4 + 1] += xv0 * wv.y;
                        acc0[o4 * 4 + 2] += xv0 * wv.z; acc0[o4 * 4 + 3] += xv0 * wv.w;
                        acc1[o4 * 4 + 0] += xv1 * wv.x; acc1[o4 * 4 + 1] += xv1 * wv.y;
                        acc1[o4 * 4 + 2] += xv1 * wv.z; acc1[o4 * 4 + 3] += xv1 * wv.w;
                    }
                }
            }
        }
        __syncthreads();
    }

    const int hw0 = (by0 + ty) * W_ + bx0 + tx;
    const int hw1 = (by0 + ty + 8) * W_ + bx0 + tx;
    const float aw0 = aw4[((size_t)(b * 4 + m)) * HW_ + hw0];
    const float aw1 = aw4[((size_t)(b * 4 + m)) * HW_ + hw1];
    float* ob = out + ((size_t)(b * C1_ + m * 32)) * HW_;
#pragma unroll
    for (int oc = 0; oc < 32; ++oc) {
        float t = tb[m * 32 + oc];
        ob[oc * HW_ + hw0] = (acc0[oc] + t) * aw0;
        ob[oc * HW_ + hw1] = (acc1[oc] + t) * aw1;
    }
}

// ------------------------------------------------------------------
extern "C" void kernel_launch(void* const* d_in, const int* in_sizes, int n_in,
                              void* d_out, int out_size, void* d_ws, size_t ws_size,
                              hipStream_t stream) {
    const float* x        = (const float*)d_in[0];
    const float* guide    = (const float*)d_in[1];
    const float* w_gm1    = (const float*)d_in[2];
    const float* b_gm1    = (const float*)d_in[3];
    const float* w_gm2    = (const float*)d_in[4];
    const float* b_gm2    = (const float*)d_in[5];
    // d_in[6..10]: w_qkv, w_ge1, b_ge1, w_ge2, b_ge2 -- mathematically unused
    const float* w_gl     = (const float*)d_in[11];
    const float* b_gl     = (const float*)d_in[12];
    const float* attn_bias= (const float*)d_in[13];
    const float* w_proj   = (const float*)d_in[14];
    const float* bn_gamma = (const float*)d_in[15];
    const float* bn_beta  = (const float*)d_in[16];
    const float* bn_mean  = (const float*)d_in[17];
    const float* bn_var   = (const float*)d_in[18];

    char* wsb = (char*)d_ws;
    float* fac = (float*)(wsb + OFF_FAC);
    float* imp = (float*)(wsb + OFF_IMP);
    float* aw4 = (float*)(wsb + OFF_AW4);
    float* g   = (float*)(wsb + OFF_G);
    float* tb  = (float*)(wsb + OFF_TB);
    float* wt  = (float*)(wsb + OFF_WT);
    unsigned short* wpk = (unsigned short*)(wsb + OFF_WPK);
    unsigned short* xh  = (unsigned short*)(wsb + OFF_XH);

    float* out0 = (float*)d_out;
    float* out1 = (float*)d_out + (size_t)B_ * C1_ * HW_;
    float* mx4  = (float*)d_out;   // scratch in d_out; k2 consumes, k5 overwrites

    const bool fast = (ws_size >= WS_NEED_FAST);

    k_prep<<<dim3(1280), dim3(256), 0, stream>>>(w_proj, bn_gamma, bn_beta, bn_mean,
                                                 bn_var, guide, w_gl, b_gl,
                                                 wt, tb, wpk, g);
    if (fast) {
        k14_fused<<<dim3(200, 8), dim3(256), 0, stream>>>(x, g, w_gm1, b_gm1,
                                                          w_gm2, b_gm2, attn_bias,
                                                          imp, fac, aw4, out1, mx4, xh);
        k2_topk<<<dim3(8), dim3(1024), 0, stream>>>(imp, fac, mx4, aw4, out1,
                                                    attn_bias, 1);
        k5_mfma<<<dim3(10, 20, 8), dim3(512), 0, stream>>>(xh, fac, wpk, tb, aw4, out0);
    } else {
        k1_mod<<<dim3(50, 8), dim3(256), 0, stream>>>(x, w_gm1, b_gm1, w_gm2, b_gm2,
                                                      fac, imp);
        k2_topk<<<dim3(8), dim3(1024), 0, stream>>>(imp, fac, nullptr, nullptr, nullptr,
                                                    attn_bias, 0);
        k4_aw<<<dim3(100, 8), dim3(256), 0, stream>>>(x, fac, g, attn_bias, aw4, out1);
        k5_conv<<<dim3(5, 10, B_ * 4), dim3(32, 8), 0, stream>>>(x, fac, wt, tb, aw4, out0);
    }
}